// Round 1
// baseline (11397.250 us; speedup 1.0000x reference)
//
#include <hip/hip_runtime.h>

// GCN: h1 = relu(Ahat @ (x@W1) + b1); h2 = relu(Ahat @ (h1@W2) + b2); out = h2@fc_w + fc_b
// Ahat = D^-1/2 (A + I) D^-1/2, deg from dst counts (+1 self loop).

#define N_NODES 100000
constexpr int D_IN  = 512;
constexpr int D_H   = 256;
constexpr int D_OUT = 128;

__global__ __launch_bounds__(256) void count_deg_k(const int* __restrict__ dst,
                                                   float* __restrict__ deg, int E) {
  int i = blockIdx.x * 256 + threadIdx.x;
  if (i < E) atomicAdd(&deg[dst[i]], 1.0f);
}

__global__ __launch_bounds__(256) void finish_dis_k(float* __restrict__ deg, int n) {
  int i = blockIdx.x * 256 + threadIdx.x;
  if (i < n) deg[i] = rsqrtf(deg[i] + 1.0f);  // self-loop: deg+1 >= 1 always
}

// C[M,N] = A[M,K] @ B[K,N]; optional bias add. Row-major everything.
// 64x64 tile, BK=16, 256 threads, 4x4 micro-tile per thread.
template<bool ADD_BIAS>
__global__ __launch_bounds__(256) void gemm_k(const float* __restrict__ A,
                                              const float* __restrict__ B,
                                              const float* __restrict__ bias,
                                              float* __restrict__ C,
                                              int M, int K, int N) {
  constexpr int BM = 64, BN = 64, BK = 16;
  __shared__ float As[BK][BM + 4];  // transposed A tile, padded
  __shared__ float Bs[BK][BN];

  const int tid = threadIdx.x;
  const int tx = tid & 15, ty = tid >> 4;
  const int row0 = blockIdx.y * BM, col0 = blockIdx.x * BN;

  // global load mapping
  const int arow  = tid >> 2;         // 0..63
  const int acol4 = (tid & 3) * 4;    // 0,4,8,12
  const int brow  = tid >> 4;         // 0..15
  const int bcol4 = (tid & 15) * 4;   // 0..60

  float acc[4][4] = {};

  for (int k0 = 0; k0 < K; k0 += BK) {
    const int ar = row0 + arow;
    float4 av = make_float4(0.f, 0.f, 0.f, 0.f);
    if (ar < M) av = *(const float4*)(A + (size_t)ar * K + k0 + acol4);
    As[acol4 + 0][arow] = av.x;
    As[acol4 + 1][arow] = av.y;
    As[acol4 + 2][arow] = av.z;
    As[acol4 + 3][arow] = av.w;

    float4 bv = *(const float4*)(B + (size_t)(k0 + brow) * N + col0 + bcol4);
    *(float4*)&Bs[brow][bcol4] = bv;

    __syncthreads();
#pragma unroll
    for (int kk = 0; kk < BK; ++kk) {
      float a[4], b[4];
#pragma unroll
      for (int i = 0; i < 4; ++i) a[i] = As[kk][ty * 4 + i];
#pragma unroll
      for (int j = 0; j < 4; ++j) b[j] = Bs[kk][tx * 4 + j];
#pragma unroll
      for (int i = 0; i < 4; ++i)
#pragma unroll
        for (int j = 0; j < 4; ++j) acc[i][j] += a[i] * b[j];
    }
    __syncthreads();
  }

#pragma unroll
  for (int i = 0; i < 4; ++i) {
    const int r = row0 + ty * 4 + i;
    if (r < M) {
#pragma unroll
      for (int j = 0; j < 4; ++j) {
        const int c = col0 + tx * 4 + j;
        float v = acc[i][j];
        if (ADD_BIAS) v += bias[c];
        C[(size_t)r * N + c] = v;
      }
    }
  }
}

// one wave (64 lanes) per edge; each lane handles 4 consecutive feats (256 total)
__global__ __launch_bounds__(256) void scatter_k(const float* __restrict__ xw,
                                                 const int* __restrict__ src,
                                                 const int* __restrict__ dst,
                                                 const float* __restrict__ dis,
                                                 float* __restrict__ agg, int E) {
  int tid = blockIdx.x * 256 + threadIdx.x;
  int e = tid >> 6, lane = tid & 63;
  if (e >= E) return;
  int s = src[e], d = dst[e];
  float w = dis[s] * dis[d];
  float4 v = *(const float4*)(xw + (size_t)s * 256 + lane * 4);
  float* out = agg + (size_t)d * 256 + lane * 4;
  atomicAdd(out + 0, v.x * w);
  atomicAdd(out + 1, v.y * w);
  atomicAdd(out + 2, v.z * w);
  atomicAdd(out + 3, v.w * w);
}

// h = relu(agg + dis^2 * xw + bias), in place on agg
__global__ __launch_bounds__(256) void epilogue_k(float* __restrict__ h,
                                                  const float* __restrict__ xw,
                                                  const float* __restrict__ dis,
                                                  const float* __restrict__ bias, int n) {
  int tid = blockIdx.x * 256 + threadIdx.x;
  int v = tid >> 6, lane = tid & 63;
  if (v >= n) return;
  float d2 = dis[v] * dis[v];
  size_t base = (size_t)v * 256 + lane * 4;
  float4 a = *(float4*)(h + base);
  float4 x = *(const float4*)(xw + base);
  float4 b = *(const float4*)(bias + lane * 4);
  float4 o;
  o.x = fmaxf(fmaf(d2, x.x, a.x) + b.x, 0.f);
  o.y = fmaxf(fmaf(d2, x.y, a.y) + b.y, 0.f);
  o.z = fmaxf(fmaf(d2, x.z, a.z) + b.z, 0.f);
  o.w = fmaxf(fmaf(d2, x.w, a.w) + b.w, 0.f);
  *(float4*)(h + base) = o;
}

extern "C" void kernel_launch(void* const* d_in, const int* in_sizes, int n_in,
                              void* d_out, int out_size, void* d_ws, size_t ws_size,
                              hipStream_t stream) {
  const float* x    = (const float*)d_in[0];
  const int*   ei   = (const int*)d_in[1];
  const float* W1   = (const float*)d_in[2];
  const float* b1   = (const float*)d_in[3];
  const float* W2   = (const float*)d_in[4];
  const float* b2   = (const float*)d_in[5];
  const float* fc_w = (const float*)d_in[6];
  const float* fc_b = (const float*)d_in[7];
  float* out = (float*)d_out;

  const int E = in_sizes[1] / 2;
  const int* src = ei;       // edge_index[0]
  const int* dst = ei + E;   // edge_index[1]

  float* dis  = (float*)d_ws;                       // N floats (deg then dis, in place)
  float* bufA = dis + (1 << 17);                    // N*256 floats (xw)
  float* bufB = bufA + (size_t)N_NODES * 256;       // N*256 floats (agg/h)

  // degree + normalization
  hipMemsetAsync(dis, 0, N_NODES * sizeof(float), stream);
  count_deg_k<<<(E + 255) / 256, 256, 0, stream>>>(dst, dis, E);
  finish_dis_k<<<(N_NODES + 255) / 256, 256, 0, stream>>>(dis, N_NODES);

  const int edge_blocks = (E * 64 + 255) / 256;
  const int node_blocks = (N_NODES * 64 + 255) / 256;

  // ---- layer 1 ----
  {
    dim3 g(D_H / 64, (N_NODES + 63) / 64);
    gemm_k<false><<<g, 256, 0, stream>>>(x, W1, nullptr, bufA, N_NODES, D_IN, D_H);
  }
  hipMemsetAsync(bufB, 0, (size_t)N_NODES * D_H * sizeof(float), stream);
  scatter_k<<<edge_blocks, 256, 0, stream>>>(bufA, src, dst, dis, bufB, E);
  epilogue_k<<<node_blocks, 256, 0, stream>>>(bufB, bufA, dis, b1, N_NODES);

  // ---- layer 2 ----
  {
    dim3 g(D_H / 64, (N_NODES + 63) / 64);
    gemm_k<false><<<g, 256, 0, stream>>>(bufB, W2, nullptr, bufA, N_NODES, D_H, D_H);
  }
  hipMemsetAsync(bufB, 0, (size_t)N_NODES * D_H * sizeof(float), stream);
  scatter_k<<<edge_blocks, 256, 0, stream>>>(bufA, src, dst, dis, bufB, E);
  epilogue_k<<<node_blocks, 256, 0, stream>>>(bufB, bufA, dis, b2, N_NODES);

  // ---- final fc ----
  {
    dim3 g(D_OUT / 64, (N_NODES + 63) / 64);
    gemm_k<true><<<g, 256, 0, stream>>>(bufB, fc_w, fc_b, out, N_NODES, D_H, D_OUT);
  }
}

// Round 2
// 1279.372 us; speedup vs baseline: 8.9085x; 8.9085x over previous
//
#include <hip/hip_runtime.h>

// GCN: h1 = relu(Ahat @ (x@W1) + b1); h2 = relu(Ahat @ (h1@W2) + b2); out = h2@fc_w + fc_b
// Ahat = D^-1/2 (A + I) D^-1/2. Aggregation via device-built CSR (by dst) + gather,
// NO feature atomics (R0 scatter_k was atomic-RMW bound: 5.3ms each, VALUBusy 1.2%).

#define N_NODES 100000
constexpr int D_IN  = 512;
constexpr int D_H   = 256;
constexpr int D_OUT = 128;

// ---------- CSR build ----------

__global__ __launch_bounds__(256) void deg_count_k(const int* __restrict__ dst,
                                                   int* __restrict__ deg, int E) {
  int i = blockIdx.x * 256 + threadIdx.x;
  if (i < E) atomicAdd(&deg[dst[i]], 1);
}

__global__ __launch_bounds__(256) void dis_k(const int* __restrict__ deg,
                                             float* __restrict__ dis, int n) {
  int i = blockIdx.x * 256 + threadIdx.x;
  if (i < n) dis[i] = rsqrtf((float)deg[i] + 1.0f);  // +1 self loop
}

// exclusive scan of deg[0..n) into off[0..n); 1024 elems/block
__global__ __launch_bounds__(256) void scan1_k(const int* __restrict__ deg,
                                               int* __restrict__ off,
                                               int* __restrict__ bsum, int n) {
  __shared__ int ts[256];
  const int tid = threadIdx.x;
  const int base = blockIdx.x * 1024 + tid * 4;
  int v[4];
#pragma unroll
  for (int t = 0; t < 4; ++t) v[t] = (base + t < n) ? deg[base + t] : 0;
  const int tot = v[0] + v[1] + v[2] + v[3];
  ts[tid] = tot;
  __syncthreads();
  for (int o = 1; o < 256; o <<= 1) {
    int t = (tid >= o) ? ts[tid - o] : 0;
    __syncthreads();
    ts[tid] += t;
    __syncthreads();
  }
  int run = ts[tid] - tot;  // exclusive within block
#pragma unroll
  for (int t = 0; t < 4; ++t) {
    if (base + t < n) off[base + t] = run;
    run += v[t];
  }
  if (tid == 255) bsum[blockIdx.x] = ts[255];
}

__global__ __launch_bounds__(128) void scan2_k(int* __restrict__ bsum, int nb) {
  __shared__ int ts[128];
  const int tid = threadIdx.x;
  const int v = (tid < nb) ? bsum[tid] : 0;
  ts[tid] = v;
  __syncthreads();
  for (int o = 1; o < 128; o <<= 1) {
    int t = (tid >= o) ? ts[tid - o] : 0;
    __syncthreads();
    ts[tid] += t;
    __syncthreads();
  }
  if (tid < nb) bsum[tid] = ts[tid] - v;  // exclusive
}

__global__ __launch_bounds__(256) void scan3_k(int* __restrict__ off,
                                               const int* __restrict__ bsum,
                                               int n, int E) {
  int i = blockIdx.x * 256 + threadIdx.x;
  if (i < n) off[i] += bsum[i >> 10];
  if (i == 0) off[n] = E;
}

__global__ __launch_bounds__(256) void fill_k(const int* __restrict__ src,
                                              const int* __restrict__ dst,
                                              const int* __restrict__ off,
                                              int* __restrict__ cursor,
                                              int* __restrict__ ssorted, int E) {
  int e = blockIdx.x * 256 + threadIdx.x;
  if (e < E) {
    int d = dst[e];
    int p = off[d] + atomicAdd(&cursor[d], 1);
    ssorted[p] = src[e];
  }
}

// ---------- dense GEMM (fp32 VALU), 64x64 tile ----------
template<bool ADD_BIAS>
__global__ __launch_bounds__(256) void gemm_k(const float* __restrict__ A,
                                              const float* __restrict__ B,
                                              const float* __restrict__ bias,
                                              float* __restrict__ C,
                                              int M, int K, int N) {
  constexpr int BM = 64, BN = 64, BK = 16;
  __shared__ float As[BK][BM + 4];
  __shared__ float Bs[BK][BN];

  const int tid = threadIdx.x;
  const int tx = tid & 15, ty = tid >> 4;
  const int row0 = blockIdx.y * BM, col0 = blockIdx.x * BN;

  const int arow  = tid >> 2;
  const int acol4 = (tid & 3) * 4;
  const int brow  = tid >> 4;
  const int bcol4 = (tid & 15) * 4;

  float acc[4][4] = {};

  for (int k0 = 0; k0 < K; k0 += BK) {
    const int ar = row0 + arow;
    float4 av = make_float4(0.f, 0.f, 0.f, 0.f);
    if (ar < M) av = *(const float4*)(A + (size_t)ar * K + k0 + acol4);
    As[acol4 + 0][arow] = av.x;
    As[acol4 + 1][arow] = av.y;
    As[acol4 + 2][arow] = av.z;
    As[acol4 + 3][arow] = av.w;

    float4 bv = *(const float4*)(B + (size_t)(k0 + brow) * N + col0 + bcol4);
    *(float4*)&Bs[brow][bcol4] = bv;

    __syncthreads();
#pragma unroll
    for (int kk = 0; kk < BK; ++kk) {
      float a[4], b[4];
#pragma unroll
      for (int i = 0; i < 4; ++i) a[i] = As[kk][ty * 4 + i];
#pragma unroll
      for (int j = 0; j < 4; ++j) b[j] = Bs[kk][tx * 4 + j];
#pragma unroll
      for (int i = 0; i < 4; ++i)
#pragma unroll
        for (int j = 0; j < 4; ++j) acc[i][j] += a[i] * b[j];
    }
    __syncthreads();
  }

#pragma unroll
  for (int i = 0; i < 4; ++i) {
    const int r = row0 + ty * 4 + i;
    if (r < M) {
#pragma unroll
      for (int j = 0; j < 4; ++j) {
        const int c = col0 + tx * 4 + j;
        float v = acc[i][j];
        if (ADD_BIAS) v += bias[c];
        C[(size_t)r * N + c] = v;
      }
    }
  }
}

// ---------- gather-aggregate + self-loop + bias + relu, one wave per node ----------
__global__ __launch_bounds__(256) void gather_k(const float* __restrict__ xw,
                                                const int* __restrict__ ssorted,
                                                const int* __restrict__ off,
                                                const float* __restrict__ dis,
                                                const float* __restrict__ bias,
                                                float* __restrict__ out, int n) {
  const int gid = blockIdx.x * 256 + threadIdx.x;
  const int v = gid >> 6, lane = gid & 63;
  if (v >= n) return;

  const float dv = dis[v];
  const size_t fo = (size_t)lane * 4;

  // acc = dv * x_self  (self-loop folded: final = dv*(dv*x_self + sum dis[s]*x_s))
  float4 acc = *(const float4*)(xw + (size_t)v * 256 + fo);
  acc.x *= dv; acc.y *= dv; acc.z *= dv; acc.w *= dv;

  const int beg = off[v], end = off[v + 1];
  const int ne = end - beg;

  for (int j0 = 0; j0 < ne; j0 += 64) {
    const int rem = ne - j0;
    const int cnt = rem < 64 ? rem : 64;
    int s_l = 0;
    float w_l = 0.f;
    if (lane < cnt) {
      s_l = ssorted[beg + j0 + lane];
      w_l = dis[s_l];
    }
    for (int k = 0; k < cnt; ++k) {
      const int s = __shfl(s_l, k);
      const float w = __shfl(w_l, k);
      const float4 xv = *(const float4*)(xw + (size_t)s * 256 + fo);
      acc.x = fmaf(w, xv.x, acc.x);
      acc.y = fmaf(w, xv.y, acc.y);
      acc.z = fmaf(w, xv.z, acc.z);
      acc.w = fmaf(w, xv.w, acc.w);
    }
  }

  const float4 b = *(const float4*)(bias + lane * 4);
  float4 o;
  o.x = fmaxf(fmaf(dv, acc.x, b.x), 0.f);
  o.y = fmaxf(fmaf(dv, acc.y, b.y), 0.f);
  o.z = fmaxf(fmaf(dv, acc.z, b.z), 0.f);
  o.w = fmaxf(fmaf(dv, acc.w, b.w), 0.f);
  *(float4*)(out + (size_t)v * 256 + fo) = o;
}

// ---------- launch ----------
extern "C" void kernel_launch(void* const* d_in, const int* in_sizes, int n_in,
                              void* d_out, int out_size, void* d_ws, size_t ws_size,
                              hipStream_t stream) {
  const float* x    = (const float*)d_in[0];
  const int*   ei   = (const int*)d_in[1];
  const float* W1   = (const float*)d_in[2];
  const float* b1   = (const float*)d_in[3];
  const float* W2   = (const float*)d_in[4];
  const float* b2   = (const float*)d_in[5];
  const float* fc_w = (const float*)d_in[6];
  const float* fc_b = (const float*)d_in[7];
  float* out = (float*)d_out;

  const int E = in_sizes[1] / 2;
  const int* src = ei;
  const int* dst = ei + E;

  const int N = N_NODES;

  // workspace layout
  int*   deg     = (int*)d_ws;            // N ints (also reused as fill cursor)
  float* dis     = (float*)(deg + N);     // N floats
  int*   off     = (int*)(dis + N);       // N+1 ints
  int*   ssorted = off + N + 1;           // E ints
  int*   bsum    = ssorted + E;           // 128 ints
  size_t meta_bytes = ((char*)(bsum + 128)) - (char*)d_ws;
  meta_bytes = (meta_bytes + 255) & ~(size_t)255;
  float* bufA = (float*)((char*)d_ws + meta_bytes);   // N*256
  float* bufB = bufA + (size_t)N * 256;               // N*256

  const int NB1 = (N + 1023) / 1024;  // 98

  // CSR build
  hipMemsetAsync(deg, 0, N * sizeof(int), stream);
  deg_count_k<<<(E + 255) / 256, 256, 0, stream>>>(dst, deg, E);
  dis_k<<<(N + 255) / 256, 256, 0, stream>>>(deg, dis, N);
  scan1_k<<<NB1, 256, 0, stream>>>(deg, off, bsum, N);
  scan2_k<<<1, 128, 0, stream>>>(bsum, NB1);
  scan3_k<<<(N + 255) / 256, 256, 0, stream>>>(off, bsum, N, E);
  hipMemsetAsync(deg, 0, N * sizeof(int), stream);  // reuse as cursor
  fill_k<<<(E + 255) / 256, 256, 0, stream>>>(src, dst, off, deg, ssorted, E);

  const int node_wave_blocks = (N * 64 + 255) / 256;

  // layer 1
  {
    dim3 g(D_H / 64, (N + 63) / 64);
    gemm_k<false><<<g, 256, 0, stream>>>(x, W1, nullptr, bufA, N, D_IN, D_H);
  }
  gather_k<<<node_wave_blocks, 256, 0, stream>>>(bufA, ssorted, off, dis, b1, bufB, N);

  // layer 2
  {
    dim3 g(D_H / 64, (N + 63) / 64);
    gemm_k<false><<<g, 256, 0, stream>>>(bufB, W2, nullptr, bufA, N, D_H, D_H);
  }
  gather_k<<<node_wave_blocks, 256, 0, stream>>>(bufA, ssorted, off, dis, b2, bufB, N);

  // final fc
  {
    dim3 g(D_OUT / 64, (N + 63) / 64);
    gemm_k<true><<<g, 256, 0, stream>>>(bufB, fc_w, fc_b, out, N, D_H, D_OUT);
  }
}

// Round 3
// 1047.322 us; speedup vs baseline: 10.8823x; 1.2216x over previous
//
#include <hip/hip_runtime.h>

// GCN on MI355X. R2: CSR gather (no atomics), fp32 VALU GEMM (~72 TF, 635us of 1279).
// R3: GEMMs -> MFMA split-bf16 (3-term, ~fp32 precision). Gather emits h as bf16 hi/lo.

#define N_NODES 100000
constexpr int D_IN  = 512;
constexpr int D_H   = 256;
constexpr int D_OUT = 128;

typedef __attribute__((ext_vector_type(8))) short bf16x8;
typedef __attribute__((ext_vector_type(4))) float f32x4;

__device__ inline void split1(float a, unsigned short& h, unsigned short& l) {
  unsigned int u = __float_as_uint(a);
  h = (unsigned short)(u >> 16);                    // truncate -> bf16 hi
  float hf = __uint_as_float(u & 0xFFFF0000u);
  l = (unsigned short)(__float_as_uint(a - hf) >> 16);  // residual -> bf16 lo
}

// ---------- CSR build ----------

__global__ __launch_bounds__(256) void deg_count_k(const int* __restrict__ dst,
                                                   int* __restrict__ deg, int E) {
  int i = blockIdx.x * 256 + threadIdx.x;
  if (i < E) atomicAdd(&deg[dst[i]], 1);
}

__global__ __launch_bounds__(256) void dis_k(const int* __restrict__ deg,
                                             float* __restrict__ dis, int n) {
  int i = blockIdx.x * 256 + threadIdx.x;
  if (i < n) dis[i] = rsqrtf((float)deg[i] + 1.0f);
}

__global__ __launch_bounds__(256) void scan1_k(const int* __restrict__ deg,
                                               int* __restrict__ off,
                                               int* __restrict__ bsum, int n) {
  __shared__ int ts[256];
  const int tid = threadIdx.x;
  const int base = blockIdx.x * 1024 + tid * 4;
  int v[4];
#pragma unroll
  for (int t = 0; t < 4; ++t) v[t] = (base + t < n) ? deg[base + t] : 0;
  const int tot = v[0] + v[1] + v[2] + v[3];
  ts[tid] = tot;
  __syncthreads();
  for (int o = 1; o < 256; o <<= 1) {
    int t = (tid >= o) ? ts[tid - o] : 0;
    __syncthreads();
    ts[tid] += t;
    __syncthreads();
  }
  int run = ts[tid] - tot;
#pragma unroll
  for (int t = 0; t < 4; ++t) {
    if (base + t < n) off[base + t] = run;
    run += v[t];
  }
  if (tid == 255) bsum[blockIdx.x] = ts[255];
}

__global__ __launch_bounds__(128) void scan2_k(int* __restrict__ bsum, int nb) {
  __shared__ int ts[128];
  const int tid = threadIdx.x;
  const int v = (tid < nb) ? bsum[tid] : 0;
  ts[tid] = v;
  __syncthreads();
  for (int o = 1; o < 128; o <<= 1) {
    int t = (tid >= o) ? ts[tid - o] : 0;
    __syncthreads();
    ts[tid] += t;
    __syncthreads();
  }
  if (tid < nb) bsum[tid] = ts[tid] - v;
}

__global__ __launch_bounds__(256) void scan3_k(int* __restrict__ off,
                                               const int* __restrict__ bsum,
                                               int n, int E) {
  int i = blockIdx.x * 256 + threadIdx.x;
  if (i < n) off[i] += bsum[i >> 10];
  if (i == 0) off[n] = E;
}

__global__ __launch_bounds__(256) void fill_k(const int* __restrict__ src,
                                              const int* __restrict__ dst,
                                              const int* __restrict__ off,
                                              int* __restrict__ cursor,
                                              int* __restrict__ ssorted, int E) {
  int e = blockIdx.x * 256 + threadIdx.x;
  if (e < E) {
    int d = dst[e];
    int p = off[d] + atomicAdd(&cursor[d], 1);
    ssorted[p] = src[e];
  }
}

// ---------- weight transpose + split:  W[K][N] fp32 -> Wt_hi/lo[N][K] bf16 ----------
__global__ __launch_bounds__(256) void wsplit_k(const float* __restrict__ W,
                                                unsigned short* __restrict__ th,
                                                unsigned short* __restrict__ tl,
                                                int K, int logN) {
  int i = blockIdx.x * 256 + threadIdx.x;
  if (i >= (K << logN)) return;
  int k = i >> logN, n = i & ((1 << logN) - 1);
  unsigned short h, l;
  split1(W[i], h, l);
  size_t o = (size_t)n * K + k;
  th[o] = h; tl[o] = l;
}

// ---------- MFMA split-bf16 GEMM ----------
// C[M,N] = A[M,K] @ B[K,N] via 3 MFMA terms: Ah*Bh + Ah*Bl + Al*Bh.
// A: CONVERT_A ? fp32 row-major : pre-split bf16 hi/lo row-major.
// B: pre-split, transposed bf16 [N][K].
// Tile 128x64x64, 4 waves (2x2), each wave 64x32 (4x2 frags of 16x16).
// LDS XOR-swizzle (^((row&7)<<3) in shorts) kills the 128B-row-stride bank conflict (G4).
template<bool CONVERT_A, bool ADD_BIAS>
__global__ __launch_bounds__(256) void gemm_mfma_k(
    const float* __restrict__ Af32,
    const unsigned short* __restrict__ A_hi,
    const unsigned short* __restrict__ A_lo,
    const unsigned short* __restrict__ Bt_hi,
    const unsigned short* __restrict__ Bt_lo,
    const float* __restrict__ bias,
    float* __restrict__ C,
    int M, int K, int N) {
  constexpr int BM = 128, BN = 64, BK = 64;
  __shared__ short Ah[BM * BK];  // 16 KB
  __shared__ short Al[BM * BK];  // 16 KB
  __shared__ short Bh[BN * BK];  //  8 KB
  __shared__ short Bl[BN * BK];  //  8 KB

  const int tid  = threadIdx.x;
  const int wid  = tid >> 6, lane = tid & 63;
  const int wm   = wid >> 1, wn = wid & 1;
  const int row0 = blockIdx.y * BM, col0 = blockIdx.x * BN;
  const int l15  = lane & 15, l16 = lane >> 4;

  f32x4 acc[4][2];
#pragma unroll
  for (int i = 0; i < 4; ++i)
#pragma unroll
    for (int j = 0; j < 2; ++j) acc[i][j] = (f32x4){0.f, 0.f, 0.f, 0.f};

  for (int k0 = 0; k0 < K; k0 += BK) {
    // ---- stage A ----
    if (CONVERT_A) {
      // 128 rows x 64 k fp32 = 2048 float4 granules, 8/thread; convert in-flight
#pragma unroll
      for (int it = 0; it < 8; ++it) {
        int g = tid + it * 256;
        int row = g >> 4, k4 = (g & 15) * 4;
        float4 av = make_float4(0.f, 0.f, 0.f, 0.f);
        int gr = row0 + row;
        if (gr < M) av = *(const float4*)(Af32 + (size_t)gr * K + k0 + k4);
        ushort4 hi, lo;
        split1(av.x, hi.x, lo.x); split1(av.y, hi.y, lo.y);
        split1(av.z, hi.z, lo.z); split1(av.w, hi.w, lo.w);
        int off = (row * 64 + k4) ^ ((row & 7) << 3);
        *(ushort4*)&Ah[off] = hi;
        *(ushort4*)&Al[off] = lo;
      }
    } else {
      // 1024 ushort8 granules per buffer, 4/thread
#pragma unroll
      for (int it = 0; it < 4; ++it) {
        int g = tid + it * 256;
        int row = g >> 3, k8 = (g & 7) * 8;
        bf16x8 vh = {0, 0, 0, 0, 0, 0, 0, 0}, vl = {0, 0, 0, 0, 0, 0, 0, 0};
        int gr = row0 + row;
        if (gr < M) {
          size_t gi = (size_t)gr * K + k0 + k8;
          vh = *(const bf16x8*)(A_hi + gi);
          vl = *(const bf16x8*)(A_lo + gi);
        }
        int off = (row * 64 + k8) ^ ((row & 7) << 3);
        *(bf16x8*)&Ah[off] = vh;
        *(bf16x8*)&Al[off] = vl;
      }
    }
    // ---- stage B (transposed [N][K] source, 512 granules, 2/thread) ----
#pragma unroll
    for (int it = 0; it < 2; ++it) {
      int g = tid + it * 256;
      int n = g >> 3, k8 = (g & 7) * 8;
      size_t gi = (size_t)(col0 + n) * K + k0 + k8;
      bf16x8 vh = *(const bf16x8*)(Bt_hi + gi);
      bf16x8 vl = *(const bf16x8*)(Bt_lo + gi);
      int off = (n * 64 + k8) ^ ((n & 7) << 3);
      *(bf16x8*)&Bh[off] = vh;
      *(bf16x8*)&Bl[off] = vl;
    }
    __syncthreads();

    // ---- compute: 2 k-substeps of 32, 24 MFMA each per wave ----
#pragma unroll
    for (int s = 0; s < 2; ++s) {
      const int kk = s * 32 + l16 * 8;
      bf16x8 a_h[4], a_l[4], b_h[2], b_l[2];
#pragma unroll
      for (int i = 0; i < 4; ++i) {
        int row = wm * 64 + i * 16 + l15;
        int off = (row * 64 + kk) ^ ((row & 7) << 3);
        a_h[i] = *(const bf16x8*)&Ah[off];
        a_l[i] = *(const bf16x8*)&Al[off];
      }
#pragma unroll
      for (int j = 0; j < 2; ++j) {
        int nn = wn * 32 + j * 16 + l15;
        int off = (nn * 64 + kk) ^ ((nn & 7) << 3);
        b_h[j] = *(const bf16x8*)&Bh[off];
        b_l[j] = *(const bf16x8*)&Bl[off];
      }
#pragma unroll
      for (int i = 0; i < 4; ++i)
#pragma unroll
        for (int j = 0; j < 2; ++j) {
          acc[i][j] = __builtin_amdgcn_mfma_f32_16x16x32_bf16(a_h[i], b_h[j], acc[i][j], 0, 0, 0);
          acc[i][j] = __builtin_amdgcn_mfma_f32_16x16x32_bf16(a_h[i], b_l[j], acc[i][j], 0, 0, 0);
          acc[i][j] = __builtin_amdgcn_mfma_f32_16x16x32_bf16(a_l[i], b_h[j], acc[i][j], 0, 0, 0);
        }
    }
    __syncthreads();
  }

  // ---- epilogue: C/D layout col=lane&15, row=(lane>>4)*4+reg ----
#pragma unroll
  for (int j = 0; j < 2; ++j) {
    const int gcol = col0 + wn * 32 + j * 16 + l15;
    const float bv = ADD_BIAS ? bias[gcol] : 0.f;
#pragma unroll
    for (int i = 0; i < 4; ++i) {
#pragma unroll
      for (int r = 0; r < 4; ++r) {
        const int grow = row0 + wm * 64 + i * 16 + l16 * 4 + r;
        if (grow < M) C[(size_t)grow * N + gcol] = acc[i][j][r] + bv;
      }
    }
  }
}

// ---------- gather-aggregate + self-loop + bias + relu; writes bf16 hi/lo ----------
__global__ __launch_bounds__(256) void gather_k(const float* __restrict__ xw,
                                                const int* __restrict__ ssorted,
                                                const int* __restrict__ off,
                                                const float* __restrict__ dis,
                                                const float* __restrict__ bias,
                                                unsigned short* __restrict__ h_hi,
                                                unsigned short* __restrict__ h_lo,
                                                int n) {
  const int gid = blockIdx.x * 256 + threadIdx.x;
  const int v = gid >> 6, lane = gid & 63;
  if (v >= n) return;

  const float dv = dis[v];
  const size_t fo = (size_t)lane * 4;

  float4 acc = *(const float4*)(xw + (size_t)v * 256 + fo);
  acc.x *= dv; acc.y *= dv; acc.z *= dv; acc.w *= dv;

  const int beg = off[v], end = off[v + 1];
  const int ne = end - beg;

  for (int j0 = 0; j0 < ne; j0 += 64) {
    const int rem = ne - j0;
    const int cnt = rem < 64 ? rem : 64;
    int s_l = 0;
    float w_l = 0.f;
    if (lane < cnt) {
      s_l = ssorted[beg + j0 + lane];
      w_l = dis[s_l];
    }
    for (int k = 0; k < cnt; ++k) {
      const int s = __shfl(s_l, k);
      const float w = __shfl(w_l, k);
      const float4 xv = *(const float4*)(xw + (size_t)s * 256 + fo);
      acc.x = fmaf(w, xv.x, acc.x);
      acc.y = fmaf(w, xv.y, acc.y);
      acc.z = fmaf(w, xv.z, acc.z);
      acc.w = fmaf(w, xv.w, acc.w);
    }
  }

  const float4 b = *(const float4*)(bias + lane * 4);
  float4 o;
  o.x = fmaxf(fmaf(dv, acc.x, b.x), 0.f);
  o.y = fmaxf(fmaf(dv, acc.y, b.y), 0.f);
  o.z = fmaxf(fmaf(dv, acc.z, b.z), 0.f);
  o.w = fmaxf(fmaf(dv, acc.w, b.w), 0.f);

  ushort4 hh, ll;
  split1(o.x, hh.x, ll.x); split1(o.y, hh.y, ll.y);
  split1(o.z, hh.z, ll.z); split1(o.w, hh.w, ll.w);
  *(ushort4*)(h_hi + (size_t)v * 256 + fo) = hh;
  *(ushort4*)(h_lo + (size_t)v * 256 + fo) = ll;
}

// ---------- launch ----------
extern "C" void kernel_launch(void* const* d_in, const int* in_sizes, int n_in,
                              void* d_out, int out_size, void* d_ws, size_t ws_size,
                              hipStream_t stream) {
  const float* x    = (const float*)d_in[0];
  const int*   ei   = (const int*)d_in[1];
  const float* W1   = (const float*)d_in[2];
  const float* b1   = (const float*)d_in[3];
  const float* W2   = (const float*)d_in[4];
  const float* b2   = (const float*)d_in[5];
  const float* fc_w = (const float*)d_in[6];
  const float* fc_b = (const float*)d_in[7];
  float* out = (float*)d_out;

  const int E = in_sizes[1] / 2;
  const int* src = ei;
  const int* dst = ei + E;
  const int N = N_NODES;

  // workspace layout
  char* p = (char*)d_ws;
  int*   deg     = (int*)p;            p += (size_t)N * 4;
  float* dis     = (float*)p;          p += (size_t)N * 4;
  int*   off     = (int*)p;            p += (size_t)(N + 1) * 4;
  int*   ssorted = (int*)p;            p += (size_t)E * 4;
  int*   bsum    = (int*)p;            p += 512;
  p = (char*)(((size_t)p + 255) & ~(size_t)255);
  unsigned short* w1t_h = (unsigned short*)p; p += (size_t)D_H  * D_IN * 2;
  unsigned short* w1t_l = (unsigned short*)p; p += (size_t)D_H  * D_IN * 2;
  unsigned short* w2t_h = (unsigned short*)p; p += (size_t)D_H  * D_H  * 2;
  unsigned short* w2t_l = (unsigned short*)p; p += (size_t)D_H  * D_H  * 2;
  unsigned short* fct_h = (unsigned short*)p; p += (size_t)D_OUT* D_H  * 2;
  unsigned short* fct_l = (unsigned short*)p; p += (size_t)D_OUT* D_H  * 2;
  p = (char*)(((size_t)p + 255) & ~(size_t)255);
  float* bufA = (float*)p;             p += (size_t)N * D_H * 4;   // 102.4 MB
  unsigned short* h_hi = (unsigned short*)p; p += (size_t)N * D_H * 2;  // 51.2 MB
  unsigned short* h_lo = (unsigned short*)p; p += (size_t)N * D_H * 2;  // 51.2 MB

  // weight transpose+split (tiny)
  wsplit_k<<<(D_IN * D_H + 255) / 256, 256, 0, stream>>>(W1, w1t_h, w1t_l, D_IN, 8);
  wsplit_k<<<(D_H * D_H + 255) / 256, 256, 0, stream>>>(W2, w2t_h, w2t_l, D_H, 8);
  wsplit_k<<<(D_H * D_OUT + 255) / 256, 256, 0, stream>>>(fc_w, fct_h, fct_l, D_H, 7);

  // CSR build
  const int NB1 = (N + 1023) / 1024;
  hipMemsetAsync(deg, 0, N * sizeof(int), stream);
  deg_count_k<<<(E + 255) / 256, 256, 0, stream>>>(dst, deg, E);
  dis_k<<<(N + 255) / 256, 256, 0, stream>>>(deg, dis, N);
  scan1_k<<<NB1, 256, 0, stream>>>(deg, off, bsum, N);
  scan2_k<<<1, 128, 0, stream>>>(bsum, NB1);
  scan3_k<<<(N + 255) / 256, 256, 0, stream>>>(off, bsum, N, E);
  hipMemsetAsync(deg, 0, N * sizeof(int), stream);
  fill_k<<<(E + 255) / 256, 256, 0, stream>>>(src, dst, off, deg, ssorted, E);

  const int node_wave_blocks = (N * 64 + 255) / 256;
  const int MB = (N + 127) / 128;  // 782

  // layer 1: xw = x @ W1 (fp32 A converted in-staging)
  {
    dim3 g(D_H / 64, MB);
    gemm_mfma_k<true, false><<<g, 256, 0, stream>>>(
        x, nullptr, nullptr, w1t_h, w1t_l, nullptr, bufA, N, D_IN, D_H);
  }
  gather_k<<<node_wave_blocks, 256, 0, stream>>>(bufA, ssorted, off, dis, b1, h_hi, h_lo, N);

  // layer 2: xw = h1 @ W2 (pre-split A)
  {
    dim3 g(D_H / 64, MB);
    gemm_mfma_k<false, false><<<g, 256, 0, stream>>>(
        nullptr, h_hi, h_lo, w2t_h, w2t_l, nullptr, bufA, N, D_H, D_H);
  }
  gather_k<<<node_wave_blocks, 256, 0, stream>>>(bufA, ssorted, off, dis, b2, h_hi, h_lo, N);

  // final fc: out = h2 @ fc_w + fc_b
  {
    dim3 g(D_OUT / 64, MB);
    gemm_mfma_k<false, true><<<g, 256, 0, stream>>>(
        nullptr, h_hi, h_lo, fct_h, fct_l, fc_b, out, N, D_H, D_OUT);
  }
}

// Round 4
// 944.702 us; speedup vs baseline: 12.0644x; 1.1086x over previous
//
#include <hip/hip_runtime.h>

// GCN on MI355X.
// R2: CSR gather (no atomics). R3: split-bf16 MFMA GEMM (3-term), latency-bound
// (MfmaUtil 12%, VALUBusy 17%, occ 30% -- 2-barrier no-prefetch structure).
// R4: BN=256 full-width GEMM (A fetched once), 8-wave 2-phase reg-staged pipeline,
//     96 MFMA/wave per barrier-pair; gather inner loop unrolled x8 for MLP.

#define N_NODES 100000
constexpr int D_IN  = 512;
constexpr int D_H   = 256;
constexpr int D_OUT = 128;

typedef __attribute__((ext_vector_type(8))) short bf16x8;
typedef __attribute__((ext_vector_type(4))) float f32x4;

__device__ inline void split1(float a, unsigned short& h, unsigned short& l) {
  unsigned int u = __float_as_uint(a);
  h = (unsigned short)(u >> 16);                       // truncate -> bf16 hi
  float hf = __uint_as_float(u & 0xFFFF0000u);
  l = (unsigned short)(__float_as_uint(a - hf) >> 16); // residual -> bf16 lo
}

// ---------- CSR build ----------

__global__ __launch_bounds__(256) void deg_count_k(const int* __restrict__ dst,
                                                   int* __restrict__ deg, int E) {
  int i = blockIdx.x * 256 + threadIdx.x;
  if (i < E) atomicAdd(&deg[dst[i]], 1);
}

__global__ __launch_bounds__(256) void dis_k(const int* __restrict__ deg,
                                             float* __restrict__ dis, int n) {
  int i = blockIdx.x * 256 + threadIdx.x;
  if (i < n) dis[i] = rsqrtf((float)deg[i] + 1.0f);
}

__global__ __launch_bounds__(256) void scan1_k(const int* __restrict__ deg,
                                               int* __restrict__ off,
                                               int* __restrict__ bsum, int n) {
  __shared__ int ts[256];
  const int tid = threadIdx.x;
  const int base = blockIdx.x * 1024 + tid * 4;
  int v[4];
#pragma unroll
  for (int t = 0; t < 4; ++t) v[t] = (base + t < n) ? deg[base + t] : 0;
  const int tot = v[0] + v[1] + v[2] + v[3];
  ts[tid] = tot;
  __syncthreads();
  for (int o = 1; o < 256; o <<= 1) {
    int t = (tid >= o) ? ts[tid - o] : 0;
    __syncthreads();
    ts[tid] += t;
    __syncthreads();
  }
  int run = ts[tid] - tot;
#pragma unroll
  for (int t = 0; t < 4; ++t) {
    if (base + t < n) off[base + t] = run;
    run += v[t];
  }
  if (tid == 255) bsum[blockIdx.x] = ts[255];
}

__global__ __launch_bounds__(128) void scan2_k(int* __restrict__ bsum, int nb) {
  __shared__ int ts[128];
  const int tid = threadIdx.x;
  const int v = (tid < nb) ? bsum[tid] : 0;
  ts[tid] = v;
  __syncthreads();
  for (int o = 1; o < 128; o <<= 1) {
    int t = (tid >= o) ? ts[tid - o] : 0;
    __syncthreads();
    ts[tid] += t;
    __syncthreads();
  }
  if (tid < nb) bsum[tid] = ts[tid] - v;
}

__global__ __launch_bounds__(256) void scan3_k(int* __restrict__ off,
                                               const int* __restrict__ bsum,
                                               int n, int E) {
  int i = blockIdx.x * 256 + threadIdx.x;
  if (i < n) off[i] += bsum[i >> 10];
  if (i == 0) off[n] = E;
}

__global__ __launch_bounds__(256) void fill_k(const int* __restrict__ src,
                                              const int* __restrict__ dst,
                                              const int* __restrict__ off,
                                              int* __restrict__ cursor,
                                              int* __restrict__ ssorted, int E) {
  int e = blockIdx.x * 256 + threadIdx.x;
  if (e < E) {
    int d = dst[e];
    int p = off[d] + atomicAdd(&cursor[d], 1);
    ssorted[p] = src[e];
  }
}

// ---------- weight transpose + split:  W[K][N] fp32 -> Wt_hi/lo[N][K] bf16 ----------
__global__ __launch_bounds__(256) void wsplit_k(const float* __restrict__ W,
                                                unsigned short* __restrict__ th,
                                                unsigned short* __restrict__ tl,
                                                int K, int logN) {
  int i = blockIdx.x * 256 + threadIdx.x;
  if (i >= (K << logN)) return;
  int k = i >> logN, n = i & ((1 << logN) - 1);
  unsigned short h, l;
  split1(W[i], h, l);
  size_t o = (size_t)n * K + k;
  th[o] = h; tl[o] = l;
}

// ---------- pipelined MFMA split-bf16 GEMM ----------
// C[M,BN] = A[M,K] @ B[K,BN], 3 terms Ah*Bh + Ah*Bl + Al*Bh. grid = (1, M/128).
// BM=128, BK=64, 512 threads = 8 waves (2x4), per-wave 64 x (BN/4).
// 2-phase pipeline: issue global loads(t+1) -> ds_read+MFMA(t) -> barrier ->
// ds_write(t+1) -> barrier. LDS 16B-granule XOR swizzle (row&7) -> conflict-free.
template<int BN, bool CONVERT_A, bool ADD_BIAS>
__global__ __launch_bounds__(512, 2) void gemm_pipe_k(
    const float* __restrict__ Af32,
    const unsigned short* __restrict__ A_hi,
    const unsigned short* __restrict__ A_lo,
    const unsigned short* __restrict__ Bt_hi,
    const unsigned short* __restrict__ Bt_lo,
    const float* __restrict__ bias,
    float* __restrict__ C,
    int M, int K) {
  constexpr int BM = 128, BK = 64;
  constexpr int FN  = BN / 64;        // frags per wave in N (4 -> BN=256, 2 -> BN=128)
  constexpr int NBG = BN / 64;        // B 16B-granules per thread per buffer

  __shared__ short Ah[BM * BK];
  __shared__ short Al[BM * BK];
  __shared__ short Bh[BN * BK];
  __shared__ short Bl[BN * BK];

  const int tid  = threadIdx.x;
  const int wid  = tid >> 6, lane = tid & 63;
  const int wm   = wid >> 2, wn = wid & 3;
  const int l15  = lane & 15, l16 = lane >> 4;
  const int row0 = blockIdx.y * BM;

  // swizzled short-index: row stride 64 shorts (128B), 16B granule ^= (row&7)
#define SWZ(row, k) ((row) * 64 + ((((k) >> 3) ^ ((row) & 7)) << 3) + ((k) & 7))

  f32x4 acc[4][FN];
#pragma unroll
  for (int i = 0; i < 4; ++i)
#pragma unroll
    for (int j = 0; j < FN; ++j) acc[i][j] = (f32x4){0.f, 0.f, 0.f, 0.f};

  float4  areg[4];
  bf16x8  ahreg[2], alreg[2];
  bf16x8  bhreg[NBG], blreg[NBG];

  const int nsteps = K >> 6;

  // ---- stage-load (global -> regs) for K-step at kt ----
  auto stage_load = [&](int kt) {
    if constexpr (CONVERT_A) {
#pragma unroll
      for (int it = 0; it < 4; ++it) {
        int idx = tid + it * 512;
        int row = idx >> 4, k4 = (idx & 15) << 2;
        int gr = row0 + row;
        float4 z = make_float4(0.f, 0.f, 0.f, 0.f);
        areg[it] = (gr < M) ? *(const float4*)(Af32 + (size_t)gr * K + kt + k4) : z;
      }
    } else {
#pragma unroll
      for (int it = 0; it < 2; ++it) {
        int idx = tid + it * 512;
        int row = idx >> 3, k8 = (idx & 7) << 3;
        int gr = row0 + row;
        bf16x8 z = {0, 0, 0, 0, 0, 0, 0, 0};
        if (gr < M) {
          size_t gi = (size_t)gr * K + kt + k8;
          ahreg[it] = *(const bf16x8*)(A_hi + gi);
          alreg[it] = *(const bf16x8*)(A_lo + gi);
        } else { ahreg[it] = z; alreg[it] = z; }
      }
    }
#pragma unroll
    for (int it = 0; it < NBG; ++it) {
      int idx = tid + it * 512;
      int n = idx >> 3, k8 = (idx & 7) << 3;
      size_t gi = (size_t)n * K + kt + k8;
      bhreg[it] = *(const bf16x8*)(Bt_hi + gi);
      blreg[it] = *(const bf16x8*)(Bt_lo + gi);
    }
  };

  // ---- stage-write (regs -> LDS, swizzled) ----
  auto stage_write = [&]() {
    if constexpr (CONVERT_A) {
#pragma unroll
      for (int it = 0; it < 4; ++it) {
        int idx = tid + it * 512;
        int row = idx >> 4, k4 = (idx & 15) << 2;
        ushort4 h, l;
        split1(areg[it].x, h.x, l.x); split1(areg[it].y, h.y, l.y);
        split1(areg[it].z, h.z, l.z); split1(areg[it].w, h.w, l.w);
        int o = SWZ(row, k4);
        *(ushort4*)&Ah[o] = h;
        *(ushort4*)&Al[o] = l;
      }
    } else {
#pragma unroll
      for (int it = 0; it < 2; ++it) {
        int idx = tid + it * 512;
        int row = idx >> 3, k8 = (idx & 7) << 3;
        int o = SWZ(row, k8);
        *(bf16x8*)&Ah[o] = ahreg[it];
        *(bf16x8*)&Al[o] = alreg[it];
      }
    }
#pragma unroll
    for (int it = 0; it < NBG; ++it) {
      int idx = tid + it * 512;
      int n = idx >> 3, k8 = (idx & 7) << 3;
      int o = SWZ(n, k8);
      *(bf16x8*)&Bh[o] = bhreg[it];
      *(bf16x8*)&Bl[o] = blreg[it];
    }
  };

  // prologue: stage step 0
  stage_load(0);
  stage_write();
  __syncthreads();

  for (int t = 0; t < nsteps; ++t) {
    if (t + 1 < nsteps) stage_load((t + 1) << 6);  // overlap with MFMA below

    // compute step t from LDS
#pragma unroll
    for (int sub = 0; sub < 2; ++sub) {
      const int ks = sub * 32 + l16 * 8;
      bf16x8 a_h[4], a_l[4], b_h[FN], b_l[FN];
#pragma unroll
      for (int i = 0; i < 4; ++i) {
        int r = wm * 64 + i * 16 + l15;
        int o = SWZ(r, ks);
        a_h[i] = *(const bf16x8*)&Ah[o];
        a_l[i] = *(const bf16x8*)&Al[o];
      }
#pragma unroll
      for (int j = 0; j < FN; ++j) {
        int n = wn * (FN * 16) + j * 16 + l15;
        int o = SWZ(n, ks);
        b_h[j] = *(const bf16x8*)&Bh[o];
        b_l[j] = *(const bf16x8*)&Bl[o];
      }
#pragma unroll
      for (int i = 0; i < 4; ++i)
#pragma unroll
        for (int j = 0; j < FN; ++j) {
          acc[i][j] = __builtin_amdgcn_mfma_f32_16x16x32_bf16(a_h[i], b_h[j], acc[i][j], 0, 0, 0);
          acc[i][j] = __builtin_amdgcn_mfma_f32_16x16x32_bf16(a_h[i], b_l[j], acc[i][j], 0, 0, 0);
          acc[i][j] = __builtin_amdgcn_mfma_f32_16x16x32_bf16(a_l[i], b_h[j], acc[i][j], 0, 0, 0);
        }
    }

    if (t + 1 < nsteps) {
      __syncthreads();   // everyone done reading LDS(t)
      stage_write();     // compiler waits vmcnt on reg use
      __syncthreads();
    }
  }

  // epilogue: C/D layout col=lane&15, row=(lane>>4)*4+reg
#pragma unroll
  for (int j = 0; j < FN; ++j) {
    const int gcol = wn * (FN * 16) + j * 16 + l15;
    const float bv = ADD_BIAS ? bias[gcol] : 0.f;
#pragma unroll
    for (int i = 0; i < 4; ++i)
#pragma unroll
      for (int r = 0; r < 4; ++r) {
        const int grow = row0 + wm * 64 + i * 16 + l16 * 4 + r;
        if (grow < M) C[(size_t)grow * BN + gcol] = acc[i][j][r] + bv;
      }
  }
#undef SWZ
}

// ---------- gather-aggregate + self-loop + bias + relu; writes bf16 hi/lo ----------
// one wave per node; inner loop unrolled x8 -> 8 outstanding 1KB gathers per wave
__global__ __launch_bounds__(256) void gather_k(const float* __restrict__ xw,
                                                const int* __restrict__ ssorted,
                                                const int* __restrict__ off,
                                                const float* __restrict__ dis,
                                                const float* __restrict__ bias,
                                                unsigned short* __restrict__ h_hi,
                                                unsigned short* __restrict__ h_lo,
                                                int n) {
  const int gid = blockIdx.x * 256 + threadIdx.x;
  const int v = gid >> 6, lane = gid & 63;
  if (v >= n) return;

  const float dv = dis[v];
  const size_t fo = (size_t)lane * 4;

  float4 acc = *(const float4*)(xw + (size_t)v * 256 + fo);
  acc.x *= dv; acc.y *= dv; acc.z *= dv; acc.w *= dv;

  const int beg = off[v], end = off[v + 1];
  const int ne = end - beg;

  for (int j0 = 0; j0 < ne; j0 += 64) {
    const int rem = ne - j0;
    const int cnt = rem < 64 ? rem : 64;
    int s_l = 0;
    float w_l = 0.f;
    if (lane < cnt) {
      s_l = ssorted[beg + j0 + lane];
      w_l = dis[s_l];
    }
    int k = 0;
    for (; k + 8 <= cnt; k += 8) {
      float4 xv[8];
      float  w[8];
#pragma unroll
      for (int u = 0; u < 8; ++u) {
        const int s = __shfl(s_l, k + u);
        w[u] = __shfl(w_l, k + u);
        xv[u] = *(const float4*)(xw + (size_t)s * 256 + fo);
      }
#pragma unroll
      for (int u = 0; u < 8; ++u) {
        acc.x = fmaf(w[u], xv[u].x, acc.x);
        acc.y = fmaf(w[u], xv[u].y, acc.y);
        acc.z = fmaf(w[u], xv[u].z, acc.z);
        acc.w = fmaf(w[u], xv[u].w, acc.w);
      }
    }
    for (; k < cnt; ++k) {
      const int s = __shfl(s_l, k);
      const float w = __shfl(w_l, k);
      const float4 xv = *(const float4*)(xw + (size_t)s * 256 + fo);
      acc.x = fmaf(w, xv.x, acc.x);
      acc.y = fmaf(w, xv.y, acc.y);
      acc.z = fmaf(w, xv.z, acc.z);
      acc.w = fmaf(w, xv.w, acc.w);
    }
  }

  const float4 b = *(const float4*)(bias + lane * 4);
  float4 o;
  o.x = fmaxf(fmaf(dv, acc.x, b.x), 0.f);
  o.y = fmaxf(fmaf(dv, acc.y, b.y), 0.f);
  o.z = fmaxf(fmaf(dv, acc.z, b.z), 0.f);
  o.w = fmaxf(fmaf(dv, acc.w, b.w), 0.f);

  ushort4 hh, ll;
  split1(o.x, hh.x, ll.x); split1(o.y, hh.y, ll.y);
  split1(o.z, hh.z, ll.z); split1(o.w, hh.w, ll.w);
  *(ushort4*)(h_hi + (size_t)v * 256 + fo) = hh;
  *(ushort4*)(h_lo + (size_t)v * 256 + fo) = ll;
}

// ---------- launch ----------
extern "C" void kernel_launch(void* const* d_in, const int* in_sizes, int n_in,
                              void* d_out, int out_size, void* d_ws, size_t ws_size,
                              hipStream_t stream) {
  const float* x    = (const float*)d_in[0];
  const int*   ei   = (const int*)d_in[1];
  const float* W1   = (const float*)d_in[2];
  const float* b1   = (const float*)d_in[3];
  const float* W2   = (const float*)d_in[4];
  const float* b2   = (const float*)d_in[5];
  const float* fc_w = (const float*)d_in[6];
  const float* fc_b = (const float*)d_in[7];
  float* out = (float*)d_out;

  const int E = in_sizes[1] / 2;
  const int* src = ei;
  const int* dst = ei + E;
  const int N = N_NODES;

  // workspace layout
  char* p = (char*)d_ws;
  int*   deg     = (int*)p;            p += (size_t)N * 4;
  int*   cursor  = (int*)p;            p += (size_t)N * 4;   // adjacent to deg: one memset
  float* dis     = (float*)p;          p += (size_t)N * 4;
  int*   off     = (int*)p;            p += (size_t)(N + 1) * 4;
  int*   ssorted = (int*)p;            p += (size_t)E * 4;
  int*   bsum    = (int*)p;            p += 512;
  p = (char*)(((size_t)p + 255) & ~(size_t)255);
  unsigned short* w1t_h = (unsigned short*)p; p += (size_t)D_H  * D_IN * 2;
  unsigned short* w1t_l = (unsigned short*)p; p += (size_t)D_H  * D_IN * 2;
  unsigned short* w2t_h = (unsigned short*)p; p += (size_t)D_H  * D_H  * 2;
  unsigned short* w2t_l = (unsigned short*)p; p += (size_t)D_H  * D_H  * 2;
  unsigned short* fct_h = (unsigned short*)p; p += (size_t)D_OUT* D_H  * 2;
  unsigned short* fct_l = (unsigned short*)p; p += (size_t)D_OUT* D_H  * 2;
  p = (char*)(((size_t)p + 255) & ~(size_t)255);
  float* bufA = (float*)p;             p += (size_t)N * D_H * 4;        // 102.4 MB
  unsigned short* h_hi = (unsigned short*)p; p += (size_t)N * D_H * 2;  // 51.2 MB
  unsigned short* h_lo = (unsigned short*)p; p += (size_t)N * D_H * 2;  // 51.2 MB

  // weight transpose+split (tiny)
  wsplit_k<<<(D_IN * D_H + 255) / 256, 256, 0, stream>>>(W1, w1t_h, w1t_l, D_IN, 8);
  wsplit_k<<<(D_H * D_H + 255) / 256, 256, 0, stream>>>(W2, w2t_h, w2t_l, D_H, 8);
  wsplit_k<<<(D_H * D_OUT + 255) / 256, 256, 0, stream>>>(fc_w, fct_h, fct_l, D_H, 7);

  // CSR build
  const int NB1 = (N + 1023) / 1024;
  hipMemsetAsync(deg, 0, 2 * N * sizeof(int), stream);  // deg + cursor
  deg_count_k<<<(E + 255) / 256, 256, 0, stream>>>(dst, deg, E);
  dis_k<<<(N + 255) / 256, 256, 0, stream>>>(deg, dis, N);
  scan1_k<<<NB1, 256, 0, stream>>>(deg, off, bsum, N);
  scan2_k<<<1, 128, 0, stream>>>(bsum, NB1);
  scan3_k<<<(N + 255) / 256, 256, 0, stream>>>(off, bsum, N, E);
  fill_k<<<(E + 255) / 256, 256, 0, stream>>>(src, dst, off, cursor, ssorted, E);

  const int node_wave_blocks = (N * 64 + 255) / 256;
  const int MB = (N + 127) / 128;  // 782
  const dim3 gg(1, MB);

  // layer 1: xw = x @ W1 (fp32 A converted in staging)
  gemm_pipe_k<256, true, false><<<gg, 512, 0, stream>>>(
      x, nullptr, nullptr, w1t_h, w1t_l, nullptr, bufA, N, D_IN);
  gather_k<<<node_wave_blocks, 256, 0, stream>>>(bufA, ssorted, off, dis, b1, h_hi, h_lo, N);

  // layer 2: xw = h1 @ W2 (pre-split A)
  gemm_pipe_k<256, false, false><<<gg, 512, 0, stream>>>(
      nullptr, h_hi, h_lo, w2t_h, w2t_l, nullptr, bufA, N, D_H);
  gather_k<<<node_wave_blocks, 256, 0, stream>>>(bufA, ssorted, off, dis, b2, h_hi, h_lo, N);

  // final fc: out = h2 @ fc_w + fc_b
  gemm_pipe_k<128, false, true><<<gg, 512, 0, stream>>>(
      nullptr, h_hi, h_lo, fct_h, fct_l, fc_b, out, N, D_H);
}

// Round 5
// 726.218 us; speedup vs baseline: 15.6940x; 1.3009x over previous
//
#include <hip/hip_runtime.h>

// GCN on MI355X.
// R2: CSR gather (no atomics). R3: split-bf16 MFMA GEMM. R4: pipelined BN=256 GEMM;
// gather unchanged at 257us -> bytes-bound on L2-miss path (FETCH 860MB @ 3.8TB/s).
// R5: gather reads RN-bf16 rows (512B/edge, halves miss traffic); GEMM epilogue
// pre-scales rows by dis (y = dis*xw) so gather needs no dis lookup/shuffle:
// out[v] = dis[v]*(sum_{s in N(v)} y[s] + y[v]) + b.

#define N_NODES 100000
constexpr int D_IN  = 512;
constexpr int D_H   = 256;
constexpr int D_OUT = 128;

typedef __attribute__((ext_vector_type(8))) short bf16x8;
typedef __attribute__((ext_vector_type(4))) float f32x4;

__device__ inline void split1(float a, unsigned short& h, unsigned short& l) {
  unsigned int u = __float_as_uint(a);
  h = (unsigned short)(u >> 16);                       // truncate -> bf16 hi
  float hf = __uint_as_float(u & 0xFFFF0000u);
  l = (unsigned short)(__float_as_uint(a - hf) >> 16); // residual -> bf16 lo
}

__device__ inline unsigned short f2bf_rn(float f) {    // round-to-nearest-even bf16
  unsigned int u = __float_as_uint(f);
  u += 0x7FFFu + ((u >> 16) & 1u);
  return (unsigned short)(u >> 16);
}

__device__ inline float bf2f(unsigned short s) {
  return __uint_as_float(((unsigned int)s) << 16);
}

// ---------- CSR build ----------

__global__ __launch_bounds__(256) void deg_count_k(const int* __restrict__ dst,
                                                   int* __restrict__ deg, int E) {
  int i = blockIdx.x * 256 + threadIdx.x;
  if (i < E) atomicAdd(&deg[dst[i]], 1);
}

__global__ __launch_bounds__(256) void dis_k(const int* __restrict__ deg,
                                             float* __restrict__ dis, int n) {
  int i = blockIdx.x * 256 + threadIdx.x;
  if (i < n) dis[i] = rsqrtf((float)deg[i] + 1.0f);
}

__global__ __launch_bounds__(256) void scan1_k(const int* __restrict__ deg,
                                               int* __restrict__ off,
                                               int* __restrict__ bsum, int n) {
  __shared__ int ts[256];
  const int tid = threadIdx.x;
  const int base = blockIdx.x * 1024 + tid * 4;
  int v[4];
#pragma unroll
  for (int t = 0; t < 4; ++t) v[t] = (base + t < n) ? deg[base + t] : 0;
  const int tot = v[0] + v[1] + v[2] + v[3];
  ts[tid] = tot;
  __syncthreads();
  for (int o = 1; o < 256; o <<= 1) {
    int t = (tid >= o) ? ts[tid - o] : 0;
    __syncthreads();
    ts[tid] += t;
    __syncthreads();
  }
  int run = ts[tid] - tot;
#pragma unroll
  for (int t = 0; t < 4; ++t) {
    if (base + t < n) off[base + t] = run;
    run += v[t];
  }
  if (tid == 255) bsum[blockIdx.x] = ts[255];
}

__global__ __launch_bounds__(128) void scan2_k(int* __restrict__ bsum, int nb) {
  __shared__ int ts[128];
  const int tid = threadIdx.x;
  const int v = (tid < nb) ? bsum[tid] : 0;
  ts[tid] = v;
  __syncthreads();
  for (int o = 1; o < 128; o <<= 1) {
    int t = (tid >= o) ? ts[tid - o] : 0;
    __syncthreads();
    ts[tid] += t;
    __syncthreads();
  }
  if (tid < nb) bsum[tid] = ts[tid] - v;
}

__global__ __launch_bounds__(256) void scan3_k(int* __restrict__ off,
                                               const int* __restrict__ bsum,
                                               int n, int E) {
  int i = blockIdx.x * 256 + threadIdx.x;
  if (i < n) off[i] += bsum[i >> 10];
  if (i == 0) off[n] = E;
}

__global__ __launch_bounds__(256) void fill_k(const int* __restrict__ src,
                                              const int* __restrict__ dst,
                                              const int* __restrict__ off,
                                              int* __restrict__ cursor,
                                              int* __restrict__ ssorted, int E) {
  int e = blockIdx.x * 256 + threadIdx.x;
  if (e < E) {
    int d = dst[e];
    int p = off[d] + atomicAdd(&cursor[d], 1);
    ssorted[p] = src[e];
  }
}

// ---------- weight transpose + split:  W[K][N] fp32 -> Wt_hi/lo[N][K] bf16 ----------
__global__ __launch_bounds__(256) void wsplit_k(const float* __restrict__ W,
                                                unsigned short* __restrict__ th,
                                                unsigned short* __restrict__ tl,
                                                int K, int logN) {
  int i = blockIdx.x * 256 + threadIdx.x;
  if (i >= (K << logN)) return;
  int k = i >> logN, n = i & ((1 << logN) - 1);
  unsigned short h, l;
  split1(W[i], h, l);
  size_t o = (size_t)n * K + k;
  th[o] = h; tl[o] = l;
}

// ---------- pipelined MFMA split-bf16 GEMM ----------
// 3 terms Ah*Bh + Ah*Bl + Al*Bh. grid = (1, M/128). BM=128, BK=64, 512 thr = 8 waves.
// OUT_Y: write y = dis[row] * (A@B) as RN-bf16 (feeds gather). else: fp32 C + bias (fc).
template<int BN, bool CONVERT_A, bool OUT_Y>
__global__ __launch_bounds__(512, 2) void gemm_pipe_k(
    const float* __restrict__ Af32,
    const unsigned short* __restrict__ A_hi,
    const unsigned short* __restrict__ A_lo,
    const unsigned short* __restrict__ Bt_hi,
    const unsigned short* __restrict__ Bt_lo,
    const float* __restrict__ bias,
    const float* __restrict__ dis,
    float* __restrict__ C,
    unsigned short* __restrict__ Ybf,
    int M, int K) {
  constexpr int BM = 128, BK = 64;
  constexpr int FN  = BN / 64;
  constexpr int NBG = BN / 64;

  __shared__ short Ah[BM * BK];
  __shared__ short Al[BM * BK];
  __shared__ short Bh[BN * BK];
  __shared__ short Bl[BN * BK];

  const int tid  = threadIdx.x;
  const int wid  = tid >> 6, lane = tid & 63;
  const int wm   = wid >> 2, wn = wid & 3;
  const int l15  = lane & 15, l16 = lane >> 4;
  const int row0 = blockIdx.y * BM;

#define SWZ(row, k) ((row) * 64 + ((((k) >> 3) ^ ((row) & 7)) << 3) + ((k) & 7))

  f32x4 acc[4][FN];
#pragma unroll
  for (int i = 0; i < 4; ++i)
#pragma unroll
    for (int j = 0; j < FN; ++j) acc[i][j] = (f32x4){0.f, 0.f, 0.f, 0.f};

  float4  areg[4];
  bf16x8  ahreg[2], alreg[2];
  bf16x8  bhreg[NBG], blreg[NBG];

  const int nsteps = K >> 6;

  auto stage_load = [&](int kt) {
    if constexpr (CONVERT_A) {
#pragma unroll
      for (int it = 0; it < 4; ++it) {
        int idx = tid + it * 512;
        int row = idx >> 4, k4 = (idx & 15) << 2;
        int gr = row0 + row;
        float4 z = make_float4(0.f, 0.f, 0.f, 0.f);
        areg[it] = (gr < M) ? *(const float4*)(Af32 + (size_t)gr * K + kt + k4) : z;
      }
    } else {
#pragma unroll
      for (int it = 0; it < 2; ++it) {
        int idx = tid + it * 512;
        int row = idx >> 3, k8 = (idx & 7) << 3;
        int gr = row0 + row;
        bf16x8 z = {0, 0, 0, 0, 0, 0, 0, 0};
        if (gr < M) {
          size_t gi = (size_t)gr * K + kt + k8;
          ahreg[it] = *(const bf16x8*)(A_hi + gi);
          alreg[it] = *(const bf16x8*)(A_lo + gi);
        } else { ahreg[it] = z; alreg[it] = z; }
      }
    }
#pragma unroll
    for (int it = 0; it < NBG; ++it) {
      int idx = tid + it * 512;
      int n = idx >> 3, k8 = (idx & 7) << 3;
      size_t gi = (size_t)n * K + kt + k8;
      bhreg[it] = *(const bf16x8*)(Bt_hi + gi);
      blreg[it] = *(const bf16x8*)(Bt_lo + gi);
    }
  };

  auto stage_write = [&]() {
    if constexpr (CONVERT_A) {
#pragma unroll
      for (int it = 0; it < 4; ++it) {
        int idx = tid + it * 512;
        int row = idx >> 4, k4 = (idx & 15) << 2;
        ushort4 h, l;
        split1(areg[it].x, h.x, l.x); split1(areg[it].y, h.y, l.y);
        split1(areg[it].z, h.z, l.z); split1(areg[it].w, h.w, l.w);
        int o = SWZ(row, k4);
        *(ushort4*)&Ah[o] = h;
        *(ushort4*)&Al[o] = l;
      }
    } else {
#pragma unroll
      for (int it = 0; it < 2; ++it) {
        int idx = tid + it * 512;
        int row = idx >> 3, k8 = (idx & 7) << 3;
        int o = SWZ(row, k8);
        *(bf16x8*)&Ah[o] = ahreg[it];
        *(bf16x8*)&Al[o] = alreg[it];
      }
    }
#pragma unroll
    for (int it = 0; it < NBG; ++it) {
      int idx = tid + it * 512;
      int n = idx >> 3, k8 = (idx & 7) << 3;
      int o = SWZ(n, k8);
      *(bf16x8*)&Bh[o] = bhreg[it];
      *(bf16x8*)&Bl[o] = blreg[it];
    }
  };

  stage_load(0);
  stage_write();
  __syncthreads();

  for (int t = 0; t < nsteps; ++t) {
    if (t + 1 < nsteps) stage_load((t + 1) << 6);

#pragma unroll
    for (int sub = 0; sub < 2; ++sub) {
      const int ks = sub * 32 + l16 * 8;
      bf16x8 a_h[4], a_l[4], b_h[FN], b_l[FN];
#pragma unroll
      for (int i = 0; i < 4; ++i) {
        int r = wm * 64 + i * 16 + l15;
        int o = SWZ(r, ks);
        a_h[i] = *(const bf16x8*)&Ah[o];
        a_l[i] = *(const bf16x8*)&Al[o];
      }
#pragma unroll
      for (int j = 0; j < FN; ++j) {
        int n = wn * (FN * 16) + j * 16 + l15;
        int o = SWZ(n, ks);
        b_h[j] = *(const bf16x8*)&Bh[o];
        b_l[j] = *(const bf16x8*)&Bl[o];
      }
#pragma unroll
      for (int i = 0; i < 4; ++i)
#pragma unroll
        for (int j = 0; j < FN; ++j) {
          acc[i][j] = __builtin_amdgcn_mfma_f32_16x16x32_bf16(a_h[i], b_h[j], acc[i][j], 0, 0, 0);
          acc[i][j] = __builtin_amdgcn_mfma_f32_16x16x32_bf16(a_h[i], b_l[j], acc[i][j], 0, 0, 0);
          acc[i][j] = __builtin_amdgcn_mfma_f32_16x16x32_bf16(a_l[i], b_h[j], acc[i][j], 0, 0, 0);
        }
    }

    if (t + 1 < nsteps) {
      __syncthreads();
      stage_write();
      __syncthreads();
    }
  }

  // epilogue: C/D layout col=lane&15, row=(lane>>4)*4+reg
  if constexpr (OUT_Y) {
    float dvs[4][4];
#pragma unroll
    for (int i = 0; i < 4; ++i)
#pragma unroll
      for (int r = 0; r < 4; ++r) {
        const int grow = row0 + wm * 64 + i * 16 + l16 * 4 + r;
        dvs[i][r] = (grow < M) ? dis[grow] : 0.f;
      }
#pragma unroll
    for (int j = 0; j < FN; ++j) {
      const int gcol = wn * (FN * 16) + j * 16 + l15;
#pragma unroll
      for (int i = 0; i < 4; ++i)
#pragma unroll
        for (int r = 0; r < 4; ++r) {
          const int grow = row0 + wm * 64 + i * 16 + l16 * 4 + r;
          if (grow < M) Ybf[(size_t)grow * BN + gcol] = f2bf_rn(acc[i][j][r] * dvs[i][r]);
        }
    }
  } else {
#pragma unroll
    for (int j = 0; j < FN; ++j) {
      const int gcol = wn * (FN * 16) + j * 16 + l15;
      const float bv = bias[gcol];
#pragma unroll
      for (int i = 0; i < 4; ++i)
#pragma unroll
        for (int r = 0; r < 4; ++r) {
          const int grow = row0 + wm * 64 + i * 16 + l16 * 4 + r;
          if (grow < M) C[(size_t)grow * BN + gcol] = acc[i][j][r] + bv;
        }
    }
  }
#undef SWZ
}

// ---------- gather-aggregate on pre-scaled bf16 y-rows ----------
// out[v] = relu(dis[v] * (sum_{s in N(v)} y[s] + y[v]) + b); writes h hi/lo.
// one wave per node, 512B per edge (ushort4/lane), x8 unrolled.
__global__ __launch_bounds__(256) void gather_k(const unsigned short* __restrict__ y,
                                                const int* __restrict__ ssorted,
                                                const int* __restrict__ off,
                                                const float* __restrict__ dis,
                                                const float* __restrict__ bias,
                                                unsigned short* __restrict__ h_hi,
                                                unsigned short* __restrict__ h_lo,
                                                int n) {
  const int gid = blockIdx.x * 256 + threadIdx.x;
  const int v = gid >> 6, lane = gid & 63;
  if (v >= n) return;

  const float dv = dis[v];
  const int fo = lane * 4;  // shorts

  ushort4 sv = *(const ushort4*)(y + (size_t)v * 256 + fo);  // self term y[v]
  float4 acc = make_float4(bf2f(sv.x), bf2f(sv.y), bf2f(sv.z), bf2f(sv.w));

  const int beg = off[v], end = off[v + 1];
  const int ne = end - beg;

  for (int j0 = 0; j0 < ne; j0 += 64) {
    const int rem = ne - j0;
    const int cnt = rem < 64 ? rem : 64;
    int s_l = 0;
    if (lane < cnt) s_l = ssorted[beg + j0 + lane];

    int k = 0;
    for (; k + 8 <= cnt; k += 8) {
      ushort4 yv[8];
#pragma unroll
      for (int u = 0; u < 8; ++u) {
        const int s = __shfl(s_l, k + u);
        yv[u] = *(const ushort4*)(y + (size_t)s * 256 + fo);
      }
#pragma unroll
      for (int u = 0; u < 8; ++u) {
        acc.x += bf2f(yv[u].x);
        acc.y += bf2f(yv[u].y);
        acc.z += bf2f(yv[u].z);
        acc.w += bf2f(yv[u].w);
      }
    }
    for (; k < cnt; ++k) {
      const int s = __shfl(s_l, k);
      const ushort4 yv = *(const ushort4*)(y + (size_t)s * 256 + fo);
      acc.x += bf2f(yv.x);
      acc.y += bf2f(yv.y);
      acc.z += bf2f(yv.z);
      acc.w += bf2f(yv.w);
    }
  }

  const float4 b = *(const float4*)(bias + fo);
  float4 o;
  o.x = fmaxf(fmaf(dv, acc.x, b.x), 0.f);
  o.y = fmaxf(fmaf(dv, acc.y, b.y), 0.f);
  o.z = fmaxf(fmaf(dv, acc.z, b.z), 0.f);
  o.w = fmaxf(fmaf(dv, acc.w, b.w), 0.f);

  ushort4 hh, ll;
  split1(o.x, hh.x, ll.x); split1(o.y, hh.y, ll.y);
  split1(o.z, hh.z, ll.z); split1(o.w, hh.w, ll.w);
  *(ushort4*)(h_hi + (size_t)v * 256 + fo) = hh;
  *(ushort4*)(h_lo + (size_t)v * 256 + fo) = ll;
}

// ---------- launch ----------
extern "C" void kernel_launch(void* const* d_in, const int* in_sizes, int n_in,
                              void* d_out, int out_size, void* d_ws, size_t ws_size,
                              hipStream_t stream) {
  const float* x    = (const float*)d_in[0];
  const int*   ei   = (const int*)d_in[1];
  const float* W1   = (const float*)d_in[2];
  const float* b1   = (const float*)d_in[3];
  const float* W2   = (const float*)d_in[4];
  const float* b2   = (const float*)d_in[5];
  const float* fc_w = (const float*)d_in[6];
  const float* fc_b = (const float*)d_in[7];
  float* out = (float*)d_out;

  const int E = in_sizes[1] / 2;
  const int* src = ei;
  const int* dst = ei + E;
  const int N = N_NODES;

  // workspace layout
  char* p = (char*)d_ws;
  int*   deg     = (int*)p;            p += (size_t)N * 4;
  int*   cursor  = (int*)p;            p += (size_t)N * 4;   // adjacent to deg: one memset
  float* dis     = (float*)p;          p += (size_t)N * 4;
  int*   off     = (int*)p;            p += (size_t)(N + 1) * 4;
  int*   ssorted = (int*)p;            p += (size_t)E * 4;
  int*   bsum    = (int*)p;            p += 512;
  p = (char*)(((size_t)p + 255) & ~(size_t)255);
  unsigned short* w1t_h = (unsigned short*)p; p += (size_t)D_H  * D_IN * 2;
  unsigned short* w1t_l = (unsigned short*)p; p += (size_t)D_H  * D_IN * 2;
  unsigned short* w2t_h = (unsigned short*)p; p += (size_t)D_H  * D_H  * 2;
  unsigned short* w2t_l = (unsigned short*)p; p += (size_t)D_H  * D_H  * 2;
  unsigned short* fct_h = (unsigned short*)p; p += (size_t)D_OUT* D_H  * 2;
  unsigned short* fct_l = (unsigned short*)p; p += (size_t)D_OUT* D_H  * 2;
  p = (char*)(((size_t)p + 255) & ~(size_t)255);
  unsigned short* y_bf = (unsigned short*)p; p += (size_t)N * D_H * 2;  // 51.2 MB
  unsigned short* h_hi = (unsigned short*)p; p += (size_t)N * D_H * 2;  // 51.2 MB
  unsigned short* h_lo = (unsigned short*)p; p += (size_t)N * D_H * 2;  // 51.2 MB

  // weight transpose+split (tiny)
  wsplit_k<<<(D_IN * D_H + 255) / 256, 256, 0, stream>>>(W1, w1t_h, w1t_l, D_IN, 8);
  wsplit_k<<<(D_H * D_H + 255) / 256, 256, 0, stream>>>(W2, w2t_h, w2t_l, D_H, 8);
  wsplit_k<<<(D_H * D_OUT + 255) / 256, 256, 0, stream>>>(fc_w, fct_h, fct_l, D_H, 7);

  // CSR build (dis must precede layer-1 GEMM: its epilogue scales by dis)
  const int NB1 = (N + 1023) / 1024;
  hipMemsetAsync(deg, 0, 2 * N * sizeof(int), stream);  // deg + cursor
  deg_count_k<<<(E + 255) / 256, 256, 0, stream>>>(dst, deg, E);
  dis_k<<<(N + 255) / 256, 256, 0, stream>>>(deg, dis, N);
  scan1_k<<<NB1, 256, 0, stream>>>(deg, off, bsum, N);
  scan2_k<<<1, 128, 0, stream>>>(bsum, NB1);
  scan3_k<<<(N + 255) / 256, 256, 0, stream>>>(off, bsum, N, E);
  fill_k<<<(E + 255) / 256, 256, 0, stream>>>(src, dst, off, cursor, ssorted, E);

  const int node_wave_blocks = (N * 64 + 255) / 256;
  const int MB = (N + 127) / 128;  // 782
  const dim3 gg(1, MB);

  // layer 1: y = dis * (x @ W1), bf16
  gemm_pipe_k<256, true, true><<<gg, 512, 0, stream>>>(
      x, nullptr, nullptr, w1t_h, w1t_l, nullptr, dis, nullptr, y_bf, N, D_IN);
  gather_k<<<node_wave_blocks, 256, 0, stream>>>(y_bf, ssorted, off, dis, b1, h_hi, h_lo, N);

  // layer 2: y = dis * (h1 @ W2), bf16
  gemm_pipe_k<256, false, true><<<gg, 512, 0, stream>>>(
      nullptr, h_hi, h_lo, w2t_h, w2t_l, nullptr, dis, nullptr, y_bf, N, D_H);
  gather_k<<<node_wave_blocks, 256, 0, stream>>>(y_bf, ssorted, off, dis, b2, h_hi, h_lo, N);

  // final fc: out = h2 @ fc_w + fc_b (fp32)
  gemm_pipe_k<128, false, false><<<gg, 512, 0, stream>>>(
      nullptr, h_hi, h_lo, fct_h, fct_l, fc_b, nullptr, out, nullptr, N, D_H);
}

// Round 6
// 607.440 us; speedup vs baseline: 18.7627x; 1.1955x over previous
//
#include <hip/hip_runtime.h>

// GCN on MI355X.
// R2: CSR gather (no atomics). R3/R4: split-bf16 MFMA GEMM, pipelined. R5: bf16
// gather rows + dis-prescale (gather bytes-bound, halved). R6: single-term f16
// MFMA (error budget allows: absmax 1.95e-3 vs thr 6.4e-3), LDS 96->48KB ->
// 2 blocks/CU (was 1, occ 17.7%, MfmaUtil 16%); y/h buffers f16 (more precise
// than bf16, same bytes).

#define N_NODES 100000
constexpr int D_IN  = 512;
constexpr int D_H   = 256;
constexpr int D_OUT = 128;

typedef _Float16 f16x8 __attribute__((ext_vector_type(8)));
typedef _Float16 f16x4 __attribute__((ext_vector_type(4)));
typedef float f32x4 __attribute__((ext_vector_type(4)));

// ---------- CSR build ----------

__global__ __launch_bounds__(256) void deg_count_k(const int* __restrict__ dst,
                                                   int* __restrict__ deg, int E) {
  int i = blockIdx.x * 256 + threadIdx.x;
  if (i < E) atomicAdd(&deg[dst[i]], 1);
}

__global__ __launch_bounds__(256) void dis_k(const int* __restrict__ deg,
                                             float* __restrict__ dis, int n) {
  int i = blockIdx.x * 256 + threadIdx.x;
  if (i < n) dis[i] = rsqrtf((float)deg[i] + 1.0f);
}

__global__ __launch_bounds__(256) void scan1_k(const int* __restrict__ deg,
                                               int* __restrict__ off,
                                               int* __restrict__ bsum, int n) {
  __shared__ int ts[256];
  const int tid = threadIdx.x;
  const int base = blockIdx.x * 1024 + tid * 4;
  int v[4];
#pragma unroll
  for (int t = 0; t < 4; ++t) v[t] = (base + t < n) ? deg[base + t] : 0;
  const int tot = v[0] + v[1] + v[2] + v[3];
  ts[tid] = tot;
  __syncthreads();
  for (int o = 1; o < 256; o <<= 1) {
    int t = (tid >= o) ? ts[tid - o] : 0;
    __syncthreads();
    ts[tid] += t;
    __syncthreads();
  }
  int run = ts[tid] - tot;
#pragma unroll
  for (int t = 0; t < 4; ++t) {
    if (base + t < n) off[base + t] = run;
    run += v[t];
  }
  if (tid == 255) bsum[blockIdx.x] = ts[255];
}

__global__ __launch_bounds__(128) void scan2_k(int* __restrict__ bsum, int nb) {
  __shared__ int ts[128];
  const int tid = threadIdx.x;
  const int v = (tid < nb) ? bsum[tid] : 0;
  ts[tid] = v;
  __syncthreads();
  for (int o = 1; o < 128; o <<= 1) {
    int t = (tid >= o) ? ts[tid - o] : 0;
    __syncthreads();
    ts[tid] += t;
    __syncthreads();
  }
  if (tid < nb) bsum[tid] = ts[tid] - v;
}

__global__ __launch_bounds__(256) void scan3_k(int* __restrict__ off,
                                               const int* __restrict__ bsum,
                                               int n, int E) {
  int i = blockIdx.x * 256 + threadIdx.x;
  if (i < n) off[i] += bsum[i >> 10];
  if (i == 0) off[n] = E;
}

__global__ __launch_bounds__(256) void fill_k(const int* __restrict__ src,
                                              const int* __restrict__ dst,
                                              const int* __restrict__ off,
                                              int* __restrict__ cursor,
                                              int* __restrict__ ssorted, int E) {
  int e = blockIdx.x * 256 + threadIdx.x;
  if (e < E) {
    int d = dst[e];
    int p = off[d] + atomicAdd(&cursor[d], 1);
    ssorted[p] = src[e];
  }
}

// ---------- weight transpose:  W[K][N] fp32 -> Wt[N][K] f16 ----------
__global__ __launch_bounds__(256) void wtrans_k(const float* __restrict__ W,
                                                _Float16* __restrict__ T,
                                                int K, int logN) {
  int i = blockIdx.x * 256 + threadIdx.x;
  if (i >= (K << logN)) return;
  int k = i >> logN, n = i & ((1 << logN) - 1);
  T[(size_t)n * K + k] = (_Float16)W[i];
}

// ---------- pipelined f16 MFMA GEMM ----------
// C[M,BN] = A[M,K] @ B[K,BN]. grid = (1, M/128). BM=128, BK=64, 512 thr = 8 waves
// (2x4), per-wave 64x64 (4x4 frags of 16x16x32_f16).
// Single 48KB LDS buffer (2 blocks/CU), reg-staged prefetch, 2 barriers/K-step.
// OUT_Y: write y = dis[row]*(A@B) as f16 (feeds gather). else: fp32 C + bias (fc).
template<int BN, bool CONVERT_A, bool OUT_Y>
__global__ __launch_bounds__(512, 4) void gemm_pipe_k(
    const float* __restrict__ Af32,
    const _Float16* __restrict__ A16,
    const _Float16* __restrict__ Bt,
    const float* __restrict__ bias,
    const float* __restrict__ dis,
    float* __restrict__ C,
    _Float16* __restrict__ Y,
    int M, int K) {
  constexpr int BM = 128, BK = 64;
  constexpr int FN  = BN / 64;   // n-frags per wave (4 for BN=256, 2 for BN=128)
  constexpr int NBG = BN / 64;   // B 16B-granules per thread

  __shared__ _Float16 As[BM * BK];  // 16 KB
  __shared__ _Float16 Bs[BN * BK];  // 32 KB (BN=256) / 16 KB (BN=128)

  const int tid  = threadIdx.x;
  const int wid  = tid >> 6, lane = tid & 63;
  const int wm   = wid >> 2, wn = wid & 3;
  const int l15  = lane & 15, l16 = lane >> 4;
  const int row0 = blockIdx.y * BM;

  // swizzle: row stride 64 elems (128B); 16B granule (8 elems) ^= (row&7)
#define SWZ(row, k) ((row) * 64 + ((((k) >> 3) ^ ((row) & 7)) << 3) + ((k) & 7))

  f32x4 acc[4][FN];
#pragma unroll
  for (int i = 0; i < 4; ++i)
#pragma unroll
    for (int j = 0; j < FN; ++j) acc[i][j] = (f32x4){0.f, 0.f, 0.f, 0.f};

  float4 areg[2][2];     // CONVERT_A staging (2 granules x 2 float4)
  f16x8  ah16[2];        // f16-A staging
  f16x8  breg[NBG];      // B staging

  const int nsteps = K >> 6;

  auto stage_load = [&](int kt) {
    if constexpr (CONVERT_A) {
#pragma unroll
      for (int it = 0; it < 2; ++it) {
        int idx = tid + it * 512;
        int row = idx >> 3, k8 = (idx & 7) << 3;
        int gr = row0 + row;
        float4 z = make_float4(0.f, 0.f, 0.f, 0.f);
        if (gr < M) {
          const float* ap = Af32 + (size_t)gr * K + kt + k8;
          areg[it][0] = *(const float4*)ap;
          areg[it][1] = *(const float4*)(ap + 4);
        } else { areg[it][0] = z; areg[it][1] = z; }
      }
    } else {
#pragma unroll
      for (int it = 0; it < 2; ++it) {
        int idx = tid + it * 512;
        int row = idx >> 3, k8 = (idx & 7) << 3;
        int gr = row0 + row;
        if (gr < M) ah16[it] = *(const f16x8*)(A16 + (size_t)gr * K + kt + k8);
        else        ah16[it] = (f16x8){0, 0, 0, 0, 0, 0, 0, 0};
      }
    }
#pragma unroll
    for (int it = 0; it < NBG; ++it) {
      int idx = tid + it * 512;
      int n = idx >> 3, k8 = (idx & 7) << 3;
      breg[it] = *(const f16x8*)(Bt + (size_t)n * K + kt + k8);
    }
  };

  auto stage_write = [&]() {
    if constexpr (CONVERT_A) {
#pragma unroll
      for (int it = 0; it < 2; ++it) {
        int idx = tid + it * 512;
        int row = idx >> 3, k8 = (idx & 7) << 3;
        f16x8 v;
        v[0] = (_Float16)areg[it][0].x; v[1] = (_Float16)areg[it][0].y;
        v[2] = (_Float16)areg[it][0].z; v[3] = (_Float16)areg[it][0].w;
        v[4] = (_Float16)areg[it][1].x; v[5] = (_Float16)areg[it][1].y;
        v[6] = (_Float16)areg[it][1].z; v[7] = (_Float16)areg[it][1].w;
        *(f16x8*)&As[SWZ(row, k8)] = v;
      }
    } else {
#pragma unroll
      for (int it = 0; it < 2; ++it) {
        int idx = tid + it * 512;
        int row = idx >> 3, k8 = (idx & 7) << 3;
        *(f16x8*)&As[SWZ(row, k8)] = ah16[it];
      }
    }
#pragma unroll
    for (int it = 0; it < NBG; ++it) {
      int idx = tid + it * 512;
      int n = idx >> 3, k8 = (idx & 7) << 3;
      *(f16x8*)&Bs[SWZ(n, k8)] = breg[it];
    }
  };

  stage_load(0);
  stage_write();
  __syncthreads();

  for (int t = 0; t < nsteps; ++t) {
    if (t + 1 < nsteps) stage_load((t + 1) << 6);  // global->reg, flies under MFMA

#pragma unroll
    for (int sub = 0; sub < 2; ++sub) {
      const int ks = sub * 32 + l16 * 8;
      f16x8 a[4];
#pragma unroll
      for (int i = 0; i < 4; ++i)
        a[i] = *(const f16x8*)&As[SWZ(wm * 64 + i * 16 + l15, ks)];
#pragma unroll
      for (int j = 0; j < FN; ++j) {
        f16x8 b = *(const f16x8*)&Bs[SWZ(wn * (FN * 16) + j * 16 + l15, ks)];
#pragma unroll
        for (int i = 0; i < 4; ++i)
          acc[i][j] = __builtin_amdgcn_mfma_f32_16x16x32_f16(a[i], b, acc[i][j], 0, 0, 0);
      }
    }

    if (t + 1 < nsteps) {
      __syncthreads();
      stage_write();
      __syncthreads();
    }
  }

  // epilogue: C/D layout col=lane&15, row=(lane>>4)*4+reg
  if constexpr (OUT_Y) {
    float dvs[4][4];
#pragma unroll
    for (int i = 0; i < 4; ++i)
#pragma unroll
      for (int r = 0; r < 4; ++r) {
        const int grow = row0 + wm * 64 + i * 16 + l16 * 4 + r;
        dvs[i][r] = (grow < M) ? dis[grow] : 0.f;
      }
#pragma unroll
    for (int j = 0; j < FN; ++j) {
      const int gcol = wn * (FN * 16) + j * 16 + l15;
#pragma unroll
      for (int i = 0; i < 4; ++i)
#pragma unroll
        for (int r = 0; r < 4; ++r) {
          const int grow = row0 + wm * 64 + i * 16 + l16 * 4 + r;
          if (grow < M) Y[(size_t)grow * BN + gcol] = (_Float16)(acc[i][j][r] * dvs[i][r]);
        }
    }
  } else {
#pragma unroll
    for (int j = 0; j < FN; ++j) {
      const int gcol = wn * (FN * 16) + j * 16 + l15;
      const float bv = bias[gcol];
#pragma unroll
      for (int i = 0; i < 4; ++i)
#pragma unroll
        for (int r = 0; r < 4; ++r) {
          const int grow = row0 + wm * 64 + i * 16 + l16 * 4 + r;
          if (grow < M) C[(size_t)grow * BN + gcol] = acc[i][j][r] + bv;
        }
    }
  }
#undef SWZ
}

// ---------- gather-aggregate on pre-scaled f16 y-rows ----------
// out[v] = relu(dis[v] * (sum_{s in N(v)} y[s] + y[v]) + b); writes h f16.
__global__ __launch_bounds__(256) void gather_k(const _Float16* __restrict__ y,
                                                const int* __restrict__ ssorted,
                                                const int* __restrict__ off,
                                                const float* __restrict__ dis,
                                                const float* __restrict__ bias,
                                                _Float16* __restrict__ h,
                                                int n) {
  const int gid = blockIdx.x * 256 + threadIdx.x;
  const int v = gid >> 6, lane = gid & 63;
  if (v >= n) return;

  const float dv = dis[v];
  const int fo = lane * 4;

  f16x4 sv = *(const f16x4*)(y + (size_t)v * 256 + fo);  // self term y[v]
  float4 acc = make_float4((float)sv[0], (float)sv[1], (float)sv[2], (float)sv[3]);

  const int beg = off[v], end = off[v + 1];
  const int ne = end - beg;

  for (int j0 = 0; j0 < ne; j0 += 64) {
    const int rem = ne - j0;
    const int cnt = rem < 64 ? rem : 64;
    int s_l = 0;
    if (lane < cnt) s_l = ssorted[beg + j0 + lane];

    int k = 0;
    for (; k + 8 <= cnt; k += 8) {
      f16x4 yv[8];
#pragma unroll
      for (int u = 0; u < 8; ++u) {
        const int s = __shfl(s_l, k + u);
        yv[u] = *(const f16x4*)(y + (size_t)s * 256 + fo);
      }
#pragma unroll
      for (int u = 0; u < 8; ++u) {
        acc.x += (float)yv[u][0];
        acc.y += (float)yv[u][1];
        acc.z += (float)yv[u][2];
        acc.w += (float)yv[u][3];
      }
    }
    for (; k < cnt; ++k) {
      const int s = __shfl(s_l, k);
      const f16x4 yv = *(const f16x4*)(y + (size_t)s * 256 + fo);
      acc.x += (float)yv[0];
      acc.y += (float)yv[1];
      acc.z += (float)yv[2];
      acc.w += (float)yv[3];
    }
  }

  const float4 b = *(const float4*)(bias + fo);
  f16x4 o;
  o[0] = (_Float16)fmaxf(fmaf(dv, acc.x, b.x), 0.f);
  o[1] = (_Float16)fmaxf(fmaf(dv, acc.y, b.y), 0.f);
  o[2] = (_Float16)fmaxf(fmaf(dv, acc.z, b.z), 0.f);
  o[3] = (_Float16)fmaxf(fmaf(dv, acc.w, b.w), 0.f);
  *(f16x4*)(h + (size_t)v * 256 + fo) = o;
}

// ---------- launch ----------
extern "C" void kernel_launch(void* const* d_in, const int* in_sizes, int n_in,
                              void* d_out, int out_size, void* d_ws, size_t ws_size,
                              hipStream_t stream) {
  const float* x    = (const float*)d_in[0];
  const int*   ei   = (const int*)d_in[1];
  const float* W1   = (const float*)d_in[2];
  const float* b1   = (const float*)d_in[3];
  const float* W2   = (const float*)d_in[4];
  const float* b2   = (const float*)d_in[5];
  const float* fc_w = (const float*)d_in[6];
  const float* fc_b = (const float*)d_in[7];
  float* out = (float*)d_out;

  const int E = in_sizes[1] / 2;
  const int* src = ei;
  const int* dst = ei + E;
  const int N = N_NODES;

  // workspace layout
  char* p = (char*)d_ws;
  int*   deg     = (int*)p;            p += (size_t)N * 4;
  int*   cursor  = (int*)p;            p += (size_t)N * 4;   // adjacent to deg: one memset
  float* dis     = (float*)p;          p += (size_t)N * 4;
  int*   off     = (int*)p;            p += (size_t)(N + 1) * 4;
  int*   ssorted = (int*)p;            p += (size_t)E * 4;
  int*   bsum    = (int*)p;            p += 512;
  p = (char*)(((size_t)p + 255) & ~(size_t)255);
  _Float16* w1t = (_Float16*)p;        p += (size_t)D_H   * D_IN * 2;
  _Float16* w2t = (_Float16*)p;        p += (size_t)D_H   * D_H  * 2;
  _Float16* fct = (_Float16*)p;        p += (size_t)D_OUT * D_H  * 2;
  p = (char*)(((size_t)p + 255) & ~(size_t)255);
  _Float16* y16 = (_Float16*)p;        p += (size_t)N * D_H * 2;  // 51.2 MB
  _Float16* h16 = (_Float16*)p;        p += (size_t)N * D_H * 2;  // 51.2 MB

  // weight transpose to f16 (tiny)
  wtrans_k<<<(D_IN * D_H + 255) / 256, 256, 0, stream>>>(W1, w1t, D_IN, 8);
  wtrans_k<<<(D_H * D_H + 255) / 256, 256, 0, stream>>>(W2, w2t, D_H, 8);
  wtrans_k<<<(D_H * D_OUT + 255) / 256, 256, 0, stream>>>(fc_w, fct, D_H, 7);

  // CSR build (dis must precede layer-1 GEMM: epilogue scales by dis)
  const int NB1 = (N + 1023) / 1024;
  hipMemsetAsync(deg, 0, 2 * N * sizeof(int), stream);  // deg + cursor
  deg_count_k<<<(E + 255) / 256, 256, 0, stream>>>(dst, deg, E);
  dis_k<<<(N + 255) / 256, 256, 0, stream>>>(deg, dis, N);
  scan1_k<<<NB1, 256, 0, stream>>>(deg, off, bsum, N);
  scan2_k<<<1, 128, 0, stream>>>(bsum, NB1);
  scan3_k<<<(N + 255) / 256, 256, 0, stream>>>(off, bsum, N, E);
  fill_k<<<(E + 255) / 256, 256, 0, stream>>>(src, dst, off, cursor, ssorted, E);

  const int node_wave_blocks = (N * 64 + 255) / 256;
  const int MB = (N + 127) / 128;  // 782
  const dim3 gg(1, MB);

  // layer 1: y = dis * (x @ W1), f16
  gemm_pipe_k<256, true, true><<<gg, 512, 0, stream>>>(
      x, nullptr, w1t, nullptr, dis, nullptr, y16, N, D_IN);
  gather_k<<<node_wave_blocks, 256, 0, stream>>>(y16, ssorted, off, dis, b1, h16, N);

  // layer 2: y = dis * (h1 @ W2), f16
  gemm_pipe_k<256, false, true><<<gg, 512, 0, stream>>>(
      nullptr, h16, w2t, nullptr, dis, nullptr, y16, N, D_H);
  gather_k<<<node_wave_blocks, 256, 0, stream>>>(y16, ssorted, off, dis, b2, h16, N);

  // final fc: out = h2 @ fc_w + fc_b (fp32)
  gemm_pipe_k<128, false, false><<<gg, 512, 0, stream>>>(
      nullptr, h16, fct, fc_b, nullptr, out, nullptr, N, D_H);
}

// Round 7
// 534.743 us; speedup vs baseline: 21.3135x; 1.1359x over previous
//
#include <hip/hip_runtime.h>

// GCN on MI355X.
// R2: CSR gather. R3-R5: MFMA GEMM + bf16 gather + dis-prescale. R6: f16 1-term
// MFMA (absmax margin). R6 gemm1 = 157us, all pipes idle: per-step vmcnt drain
// + 4.2x write amplification (scalar 2B strided stores, L2 thrash).
// R7: BK=32 double-buffered LDS pipeline (1 barrier/step, MFMA waits lgkm only),
// LDS-staged coalesced epilogue (full-line stores).

#define N_NODES 100000
constexpr int D_IN  = 512;
constexpr int D_H   = 256;
constexpr int D_OUT = 128;

typedef _Float16 f16x8 __attribute__((ext_vector_type(8)));
typedef _Float16 f16x4 __attribute__((ext_vector_type(4)));
typedef float f32x4 __attribute__((ext_vector_type(4)));

// ---------- CSR build ----------

__global__ __launch_bounds__(256) void deg_count_k(const int* __restrict__ dst,
                                                   int* __restrict__ deg, int E) {
  int i = blockIdx.x * 256 + threadIdx.x;
  if (i < E) atomicAdd(&deg[dst[i]], 1);
}

__global__ __launch_bounds__(256) void dis_k(const int* __restrict__ deg,
                                             float* __restrict__ dis, int n) {
  int i = blockIdx.x * 256 + threadIdx.x;
  if (i < n) dis[i] = rsqrtf((float)deg[i] + 1.0f);
}

__global__ __launch_bounds__(256) void scan1_k(const int* __restrict__ deg,
                                               int* __restrict__ off,
                                               int* __restrict__ bsum, int n) {
  __shared__ int ts[256];
  const int tid = threadIdx.x;
  const int base = blockIdx.x * 1024 + tid * 4;
  int v[4];
#pragma unroll
  for (int t = 0; t < 4; ++t) v[t] = (base + t < n) ? deg[base + t] : 0;
  const int tot = v[0] + v[1] + v[2] + v[3];
  ts[tid] = tot;
  __syncthreads();
  for (int o = 1; o < 256; o <<= 1) {
    int t = (tid >= o) ? ts[tid - o] : 0;
    __syncthreads();
    ts[tid] += t;
    __syncthreads();
  }
  int run = ts[tid] - tot;
#pragma unroll
  for (int t = 0; t < 4; ++t) {
    if (base + t < n) off[base + t] = run;
    run += v[t];
  }
  if (tid == 255) bsum[blockIdx.x] = ts[255];
}

__global__ __launch_bounds__(128) void scan2_k(int* __restrict__ bsum, int nb) {
  __shared__ int ts[128];
  const int tid = threadIdx.x;
  const int v = (tid < nb) ? bsum[tid] : 0;
  ts[tid] = v;
  __syncthreads();
  for (int o = 1; o < 128; o <<= 1) {
    int t = (tid >= o) ? ts[tid - o] : 0;
    __syncthreads();
    ts[tid] += t;
    __syncthreads();
  }
  if (tid < nb) bsum[tid] = ts[tid] - v;
}

__global__ __launch_bounds__(256) void scan3_k(int* __restrict__ off,
                                               const int* __restrict__ bsum,
                                               int n, int E) {
  int i = blockIdx.x * 256 + threadIdx.x;
  if (i < n) off[i] += bsum[i >> 10];
  if (i == 0) off[n] = E;
}

__global__ __launch_bounds__(256) void fill_k(const int* __restrict__ src,
                                              const int* __restrict__ dst,
                                              const int* __restrict__ off,
                                              int* __restrict__ cursor,
                                              int* __restrict__ ssorted, int E) {
  int e = blockIdx.x * 256 + threadIdx.x;
  if (e < E) {
    int d = dst[e];
    int p = off[d] + atomicAdd(&cursor[d], 1);
    ssorted[p] = src[e];
  }
}

// ---------- weight transpose:  W[K][N] fp32 -> Wt[N][K] f16 ----------
__global__ __launch_bounds__(256) void wtrans_k(const float* __restrict__ W,
                                                _Float16* __restrict__ T,
                                                int K, int logN) {
  int i = blockIdx.x * 256 + threadIdx.x;
  if (i >= (K << logN)) return;
  int k = i >> logN, n = i & ((1 << logN) - 1);
  T[(size_t)n * K + k] = (_Float16)W[i];
}

// ---------- pipelined f16 MFMA GEMM, BK=32 double-buffered ----------
// C[M,BN] = A[M,K] @ B[K,BN]. grid = (1, M/128). BM=128, 512 thr = 8 waves (2x4),
// per-wave 64 x (16*FN), 4xFN frags of 16x16x32_f16, 16 MFMA/step (BN=256).
// Pipeline: ds_read -> MFMA (lgkm only) -> stage_write(next buf, waits own vmcnt)
// -> stage_load(t+2) -> barrier. LDS rows are 64B -> conflict-free, no swizzle.
// Epilogue: acc -> LDS f32 (padded) -> coalesced full-line global stores.
// OUT_Y: y = dis[row]*(A@B) f16. else: fp32 C = A@B + bias.
template<int BN, bool CONVERT_A, bool OUT_Y>
__global__ __launch_bounds__(512, 4) void gemm_pipe_k(
    const float* __restrict__ Af32,
    const _Float16* __restrict__ A16,
    const _Float16* __restrict__ Bt,
    const float* __restrict__ bias,
    const float* __restrict__ dis,
    float* __restrict__ C,
    _Float16* __restrict__ Y,
    int M, int K) {
  constexpr int BM = 128, BK = 32;
  constexpr int FN = BN / 64;       // 4 (BN=256) or 2 (BN=128)
  constexpr int NB = BN / 128;      // B granules per thread (2 or 1)
  constexpr int EPAD = 4;           // epilogue f32 row pad

  // LDS: stage = 2*(BM*BK + BN*BK) f16 ; epilogue = 32*(BN+EPAD) f32 (smaller)
  __shared__ __align__(16) _Float16 smem[2 * (BM + BN) * BK];
  _Float16* As = smem;              // [2][BM*BK]
  _Float16* Bs = smem + 2 * BM * BK;
  float* epi = (float*)smem;        // reused after K-loop

  const int tid  = threadIdx.x;
  const int wid  = tid >> 6, lane = tid & 63;
  const int wm   = wid >> 2, wn = wid & 3;
  const int l15  = lane & 15, l16 = lane >> 4;
  const int row0 = blockIdx.y * BM;

  f32x4 acc[4][FN];
#pragma unroll
  for (int i = 0; i < 4; ++i)
#pragma unroll
    for (int j = 0; j < FN; ++j) acc[i][j] = (f32x4){0.f, 0.f, 0.f, 0.f};

  // staging regs (1 K-step)
  const int arow = tid >> 2;            // 0..127
  const int ak8  = (tid & 3) << 3;      // 0,8,16,24
  float4 areg0, areg1;                  // CONVERT_A
  f16x8  a16reg;                        // !CONVERT_A
  f16x8  breg[NB];

  const int nsteps = K >> 5;

  auto stage_load = [&](int kt) {
    const int gr = row0 + arow;
    if constexpr (CONVERT_A) {
      if (gr < M) {
        const float* ap = Af32 + (size_t)gr * K + kt + ak8;
        areg0 = *(const float4*)ap;
        areg1 = *(const float4*)(ap + 4);
      } else {
        areg0 = make_float4(0.f, 0.f, 0.f, 0.f);
        areg1 = make_float4(0.f, 0.f, 0.f, 0.f);
      }
    } else {
      if (gr < M) a16reg = *(const f16x8*)(A16 + (size_t)gr * K + kt + ak8);
      else        a16reg = (f16x8){0, 0, 0, 0, 0, 0, 0, 0};
    }
#pragma unroll
    for (int it = 0; it < NB; ++it) {
      int idx = tid + it * 512;
      int n = idx >> 2, k8 = (idx & 3) << 3;
      breg[it] = *(const f16x8*)(Bt + (size_t)n * K + kt + k8);
    }
  };

  auto stage_write = [&](int buf) {
    _Float16* as = As + buf * (BM * BK);
    _Float16* bs = Bs + buf * (BN * BK);
    if constexpr (CONVERT_A) {
      f16x8 v;
      v[0] = (_Float16)areg0.x; v[1] = (_Float16)areg0.y;
      v[2] = (_Float16)areg0.z; v[3] = (_Float16)areg0.w;
      v[4] = (_Float16)areg1.x; v[5] = (_Float16)areg1.y;
      v[6] = (_Float16)areg1.z; v[7] = (_Float16)areg1.w;
      *(f16x8*)&as[arow * BK + ak8] = v;
    } else {
      *(f16x8*)&as[arow * BK + ak8] = a16reg;
    }
#pragma unroll
    for (int it = 0; it < NB; ++it) {
      int idx = tid + it * 512;
      int n = idx >> 2, k8 = (idx & 3) << 3;
      *(f16x8*)&bs[n * BK + k8] = breg[it];
    }
  };

  // prologue
  stage_load(0);
  stage_write(0);
  if (nsteps > 1) stage_load(BK);
  __syncthreads();

  for (int t = 0; t < nsteps; ++t) {
    const int buf = t & 1;
    const _Float16* as = As + buf * (BM * BK);
    const _Float16* bs = Bs + buf * (BN * BK);

    f16x8 a[4], b[FN];
#pragma unroll
    for (int i = 0; i < 4; ++i)
      a[i] = *(const f16x8*)&as[(wm * 64 + i * 16 + l15) * BK + l16 * 8];
#pragma unroll
    for (int j = 0; j < FN; ++j)
      b[j] = *(const f16x8*)&bs[(wn * (FN * 16) + j * 16 + l15) * BK + l16 * 8];

#pragma unroll
    for (int i = 0; i < 4; ++i)
#pragma unroll
      for (int j = 0; j < FN; ++j)
        acc[i][j] = __builtin_amdgcn_mfma_f32_16x16x32_f16(a[i], b[j], acc[i][j], 0, 0, 0);

    if (t + 1 < nsteps) {
      stage_write(buf ^ 1);                    // waits own vmcnt (loads t+1)
      if (t + 2 < nsteps) stage_load((t + 2) << 5);
    }
    __syncthreads();
  }

  // ---------- epilogue: LDS-staged coalesced stores ----------
  // 4 chunks of 32 rows; acc layout: row = wm*64 + i*16 + l16*4 + r, col = wn*FN*16 + j*16 + l15
  constexpr int ESTR = BN + EPAD;
  constexpr int CPT  = BN / 16;   // cols per thread on read side (16 or 8)
#pragma unroll
  for (int c = 0; c < 4; ++c) {
    if (wm == (c >> 1)) {
      const int ib = (c & 1) * 2;
#pragma unroll
      for (int ii = 0; ii < 2; ++ii) {
        const int i = ib + ii;
#pragma unroll
        for (int j = 0; j < FN; ++j) {
          const int col = wn * (FN * 16) + j * 16 + l15;
#pragma unroll
          for (int r = 0; r < 4; ++r) {
            const int lrow = ii * 16 + l16 * 4 + r;
            epi[lrow * ESTR + col] = acc[i][j][r];
          }
        }
      }
    }
    __syncthreads();
    {
      const int lrow = tid >> 4;
      const int grow = row0 + c * 32 + lrow;
      const int colb = (tid & 15) * CPT;
      if (grow < M) {
        float v[CPT];
#pragma unroll
        for (int q = 0; q < CPT; q += 4)
          *(float4*)&v[q] = *(const float4*)&epi[lrow * ESTR + colb + q];
        if constexpr (OUT_Y) {
          const float dv = dis[grow];
          f16x8 o[CPT / 8];
#pragma unroll
          for (int q = 0; q < CPT; ++q) o[q >> 3][q & 7] = (_Float16)(v[q] * dv);
#pragma unroll
          for (int q = 0; q < CPT / 8; ++q)
            *(f16x8*)(Y + (size_t)grow * BN + colb + q * 8) = o[q];
        } else {
#pragma unroll
          for (int q = 0; q < CPT; ++q) v[q] += bias[colb + q];
#pragma unroll
          for (int q = 0; q < CPT; q += 4)
            *(float4*)(C + (size_t)grow * BN + colb + q) = *(const float4*)&v[q];
        }
      }
    }
    __syncthreads();
  }
}

// ---------- gather-aggregate on pre-scaled f16 y-rows ----------
// out[v] = relu(dis[v] * (sum_{s in N(v)} y[s] + y[v]) + b); writes h f16.
__global__ __launch_bounds__(256) void gather_k(const _Float16* __restrict__ y,
                                                const int* __restrict__ ssorted,
                                                const int* __restrict__ off,
                                                const float* __restrict__ dis,
                                                const float* __restrict__ bias,
                                                _Float16* __restrict__ h,
                                                int n) {
  const int gid = blockIdx.x * 256 + threadIdx.x;
  const int v = gid >> 6, lane = gid & 63;
  if (v >= n) return;

  const float dv = dis[v];
  const int fo = lane * 4;

  f16x4 sv = *(const f16x4*)(y + (size_t)v * 256 + fo);  // self term y[v]
  float4 acc = make_float4((float)sv[0], (float)sv[1], (float)sv[2], (float)sv[3]);

  const int beg = off[v], end = off[v + 1];
  const int ne = end - beg;

  for (int j0 = 0; j0 < ne; j0 += 64) {
    const int rem = ne - j0;
    const int cnt = rem < 64 ? rem : 64;
    int s_l = 0;
    if (lane < cnt) s_l = ssorted[beg + j0 + lane];

    int k = 0;
    for (; k + 8 <= cnt; k += 8) {
      f16x4 yv[8];
#pragma unroll
      for (int u = 0; u < 8; ++u) {
        const int s = __shfl(s_l, k + u);
        yv[u] = *(const f16x4*)(y + (size_t)s * 256 + fo);
      }
#pragma unroll
      for (int u = 0; u < 8; ++u) {
        acc.x += (float)yv[u][0];
        acc.y += (float)yv[u][1];
        acc.z += (float)yv[u][2];
        acc.w += (float)yv[u][3];
      }
    }
    for (; k < cnt; ++k) {
      const int s = __shfl(s_l, k);
      const f16x4 yv = *(const f16x4*)(y + (size_t)s * 256 + fo);
      acc.x += (float)yv[0];
      acc.y += (float)yv[1];
      acc.z += (float)yv[2];
      acc.w += (float)yv[3];
    }
  }

  const float4 b = *(const float4*)(bias + fo);
  f16x4 o;
  o[0] = (_Float16)fmaxf(fmaf(dv, acc.x, b.x), 0.f);
  o[1] = (_Float16)fmaxf(fmaf(dv, acc.y, b.y), 0.f);
  o[2] = (_Float16)fmaxf(fmaf(dv, acc.z, b.z), 0.f);
  o[3] = (_Float16)fmaxf(fmaf(dv, acc.w, b.w), 0.f);
  *(f16x4*)(h + (size_t)v * 256 + fo) = o;
}

// ---------- launch ----------
extern "C" void kernel_launch(void* const* d_in, const int* in_sizes, int n_in,
                              void* d_out, int out_size, void* d_ws, size_t ws_size,
                              hipStream_t stream) {
  const float* x    = (const float*)d_in[0];
  const int*   ei   = (const int*)d_in[1];
  const float* W1   = (const float*)d_in[2];
  const float* b1   = (const float*)d_in[3];
  const float* W2   = (const float*)d_in[4];
  const float* b2   = (const float*)d_in[5];
  const float* fc_w = (const float*)d_in[6];
  const float* fc_b = (const float*)d_in[7];
  float* out = (float*)d_out;

  const int E = in_sizes[1] / 2;
  const int* src = ei;
  const int* dst = ei + E;
  const int N = N_NODES;

  // workspace layout
  char* p = (char*)d_ws;
  int*   deg     = (int*)p;            p += (size_t)N * 4;
  int*   cursor  = (int*)p;            p += (size_t)N * 4;   // adjacent to deg: one memset
  float* dis     = (float*)p;          p += (size_t)N * 4;
  int*   off     = (int*)p;            p += (size_t)(N + 1) * 4;
  int*   ssorted = (int*)p;            p += (size_t)E * 4;
  int*   bsum    = (int*)p;            p += 512;
  p = (char*)(((size_t)p + 255) & ~(size_t)255);
  _Float16* w1t = (_Float16*)p;        p += (size_t)D_H   * D_IN * 2;
  _Float16* w2t = (_Float16*)p;        p += (size_t)D_H   * D_H  * 2;
  _Float16* fct = (_Float16*)p;        p += (size_t)D_OUT * D_H  * 2;
  p = (char*)(((size_t)p + 255) & ~(size_t)255);
  _Float16* y16 = (_Float16*)p;        p += (size_t)N * D_H * 2;  // 51.2 MB
  _Float16* h16 = (_Float16*)p;        p += (size_t)N * D_H * 2;  // 51.2 MB

  // weight transpose to f16 (tiny)
  wtrans_k<<<(D_IN * D_H + 255) / 256, 256, 0, stream>>>(W1, w1t, D_IN, 8);
  wtrans_k<<<(D_H * D_H + 255) / 256, 256, 0, stream>>>(W2, w2t, D_H, 8);
  wtrans_k<<<(D_H * D_OUT + 255) / 256, 256, 0, stream>>>(fc_w, fct, D_H, 7);

  // CSR build (dis must precede layer-1 GEMM: epilogue scales by dis)
  const int NB1 = (N + 1023) / 1024;
  hipMemsetAsync(deg, 0, 2 * N * sizeof(int), stream);  // deg + cursor
  deg_count_k<<<(E + 255) / 256, 256, 0, stream>>>(dst, deg, E);
  dis_k<<<(N + 255) / 256, 256, 0, stream>>>(deg, dis, N);
  scan1_k<<<NB1, 256, 0, stream>>>(deg, off, bsum, N);
  scan2_k<<<1, 128, 0, stream>>>(bsum, NB1);
  scan3_k<<<(N + 255) / 256, 256, 0, stream>>>(off, bsum, N, E);
  fill_k<<<(E + 255) / 256, 256, 0, stream>>>(src, dst, off, cursor, ssorted, E);

  const int node_wave_blocks = (N * 64 + 255) / 256;
  const int MB = (N + 127) / 128;  // 782
  const dim3 gg(1, MB);

  // layer 1: y = dis * (x @ W1), f16
  gemm_pipe_k<256, true, true><<<gg, 512, 0, stream>>>(
      x, nullptr, w1t, nullptr, dis, nullptr, y16, N, D_IN);
  gather_k<<<node_wave_blocks, 256, 0, stream>>>(y16, ssorted, off, dis, b1, h16, N);

  // layer 2: y = dis * (h1 @ W2), f16
  gemm_pipe_k<256, false, true><<<gg, 512, 0, stream>>>(
      nullptr, h16, w2t, nullptr, dis, nullptr, y16, N, D_H);
  gather_k<<<node_wave_blocks, 256, 0, stream>>>(y16, ssorted, off, dis, b2, h16, N);

  // final fc: out = h2 @ fc_w + fc_b (fp32)
  gemm_pipe_k<128, false, false><<<gg, 512, 0, stream>>>(
      nullptr, h16, fct, fc_b, nullptr, out, nullptr, N, D_H);
}

// Round 8
// 519.726 us; speedup vs baseline: 21.9293x; 1.0289x over previous
//
#include <hip/hip_runtime.h>

// GCN on MI355X.
// R2: CSR gather. R3-R6: MFMA GEMM evolution -> f16 1-term. R7: BK=32 dbuf
// pipeline + coalesced epilogue (534us; gathers 2x119us now dominant and at
// the random-512B fabric floor ~6.9TB/s logical).
// R8: GEMM loads issued at TOP of step (write(t+1) slack 350->800cy, covers HBM
// latency); CSR diet (deg_count returns slot -> fill has no atomic; dis fused
// into scan1; scan3 folded into fill/gather; one wtrans kernel); 15->11 launches.

#define N_NODES 100000
constexpr int D_IN  = 512;
constexpr int D_H   = 256;
constexpr int D_OUT = 128;

typedef _Float16 f16x8 __attribute__((ext_vector_type(8)));
typedef _Float16 f16x4 __attribute__((ext_vector_type(4)));
typedef float f32x4 __attribute__((ext_vector_type(4)));

// ---------- CSR build ----------

// 4 edges/thread; stores per-edge slot (atomic return) so fill needs no atomic
__global__ __launch_bounds__(256) void deg_count_k(const int* __restrict__ dst,
                                                   int* __restrict__ deg,
                                                   int* __restrict__ pe, int E) {
  int i = (blockIdx.x * 256 + threadIdx.x) * 4;
  if (i + 3 < E) {
    int4 d = *(const int4*)(dst + i);
    int4 p;
    p.x = atomicAdd(&deg[d.x], 1);
    p.y = atomicAdd(&deg[d.y], 1);
    p.z = atomicAdd(&deg[d.z], 1);
    p.w = atomicAdd(&deg[d.w], 1);
    *(int4*)(pe + i) = p;
  } else {
    for (int t = i; t < E; ++t) pe[t] = atomicAdd(&deg[dst[t]], 1);
  }
}

// block-local exclusive scan of deg (1024/block) + dis = rsqrt(deg+1) fused
__global__ __launch_bounds__(256) void scan1_k(const int* __restrict__ deg,
                                               int* __restrict__ off,
                                               int* __restrict__ bsum,
                                               float* __restrict__ dis, int n) {
  __shared__ int ts[256];
  const int tid = threadIdx.x;
  const int base = blockIdx.x * 1024 + tid * 4;
  int v[4];
#pragma unroll
  for (int t = 0; t < 4; ++t) v[t] = (base + t < n) ? deg[base + t] : 0;
#pragma unroll
  for (int t = 0; t < 4; ++t)
    if (base + t < n) dis[base + t] = rsqrtf((float)v[t] + 1.0f);
  const int tot = v[0] + v[1] + v[2] + v[3];
  ts[tid] = tot;
  __syncthreads();
  for (int o = 1; o < 256; o <<= 1) {
    int t = (tid >= o) ? ts[tid - o] : 0;
    __syncthreads();
    ts[tid] += t;
    __syncthreads();
  }
  int run = ts[tid] - tot;
#pragma unroll
  for (int t = 0; t < 4; ++t) {
    if (base + t < n) off[base + t] = run;
    run += v[t];
  }
  if (tid == 255) bsum[blockIdx.x] = ts[255];
}

__global__ __launch_bounds__(128) void scan2_k(int* __restrict__ bsum, int nb) {
  __shared__ int ts[128];
  const int tid = threadIdx.x;
  const int v = (tid < nb) ? bsum[tid] : 0;
  ts[tid] = v;
  __syncthreads();
  for (int o = 1; o < 128; o <<= 1) {
    int t = (tid >= o) ? ts[tid - o] : 0;
    __syncthreads();
    ts[tid] += t;
    __syncthreads();
  }
  if (tid < nb) bsum[tid] = ts[tid] - v;
}

// position = off[d] + bsum[d>>10] + pe[e]; no atomics
__global__ __launch_bounds__(256) void fill_k(const int* __restrict__ src,
                                              const int* __restrict__ dst,
                                              const int* __restrict__ pe,
                                              const int* __restrict__ off,
                                              const int* __restrict__ bsum,
                                              int* __restrict__ ssorted, int E) {
  int i = (blockIdx.x * 256 + threadIdx.x) * 4;
  if (i + 3 < E) {
    int4 s = *(const int4*)(src + i);
    int4 d = *(const int4*)(dst + i);
    int4 p = *(const int4*)(pe + i);
    ssorted[off[d.x] + bsum[d.x >> 10] + p.x] = s.x;
    ssorted[off[d.y] + bsum[d.y >> 10] + p.y] = s.y;
    ssorted[off[d.z] + bsum[d.z >> 10] + p.z] = s.z;
    ssorted[off[d.w] + bsum[d.w >> 10] + p.w] = s.w;
  } else {
    for (int t = i; t < E; ++t) {
      int d = dst[t];
      ssorted[off[d] + bsum[d >> 10] + pe[t]] = src[t];
    }
  }
}

// ---------- all three weight transposes (fp32 [K][N] -> f16 [N][K]) in one ----------
__global__ __launch_bounds__(256) void wtrans_all_k(const float* __restrict__ W1,
                                                    const float* __restrict__ W2,
                                                    const float* __restrict__ FC,
                                                    _Float16* __restrict__ w1t,
                                                    _Float16* __restrict__ w2t,
                                                    _Float16* __restrict__ fct) {
  int i = blockIdx.x * 256 + threadIdx.x;
  if (i < 131072) {                       // W1: 512x256
    int k = i >> 8, n = i & 255;
    w1t[(size_t)n * 512 + k] = (_Float16)W1[i];
  } else if (i < 196608) {                // W2: 256x256
    int j = i - 131072;
    int k = j >> 8, n = j & 255;
    w2t[(size_t)n * 256 + k] = (_Float16)W2[j];
  } else if (i < 229376) {                // fc_w: 256x128
    int j = i - 196608;
    int k = j >> 7, n = j & 127;
    fct[(size_t)n * 256 + k] = (_Float16)FC[j];
  }
}

// ---------- pipelined f16 MFMA GEMM, BK=32 double-buffered, load-at-top ----------
// C[M,BN] = A[M,K] @ B[K,BN]. grid = (1, ceil(M/128)). BM=128, 512 thr = 8 waves
// (2x4), per-wave 64 x (16*FN). Step t: issue loads(t+2) -> ds_read+MFMA(t) ->
// stage_write(t+1, other buf) -> barrier. Named register sets (no dyn indexing).
// OUT_Y: y = dis[row]*(A@B) f16. else: fp32 C = A@B + bias.
template<int BN, bool CONVERT_A, bool OUT_Y>
__global__ __launch_bounds__(512, 4) void gemm_pipe_k(
    const float* __restrict__ Af32,
    const _Float16* __restrict__ A16,
    const _Float16* __restrict__ Bt,
    const float* __restrict__ bias,
    const float* __restrict__ dis,
    float* __restrict__ C,
    _Float16* __restrict__ Y,
    int M, int K) {
  constexpr int BM = 128, BK = 32;
  constexpr int FN = BN / 64;       // 4 (BN=256) or 2 (BN=128)
  constexpr int NB = BN / 128;      // B granules per thread (2 or 1)
  constexpr int EPAD = 8;           // epilogue f32 row pad (diagonal banks)

  __shared__ __align__(16) _Float16 smem[2 * (BM + BN) * BK];
  _Float16* As = smem;              // [2][BM*BK]
  _Float16* Bs = smem + 2 * BM * BK;
  float* epi = (float*)smem;        // reused after K-loop

  const int tid  = threadIdx.x;
  const int wid  = tid >> 6, lane = tid & 63;
  const int wm   = wid >> 2, wn = wid & 3;
  const int l15  = lane & 15, l16 = lane >> 4;
  const int row0 = blockIdx.y * BM;

  f32x4 acc[4][FN];
#pragma unroll
  for (int i = 0; i < 4; ++i)
#pragma unroll
    for (int j = 0; j < FN; ++j) acc[i][j] = (f32x4){0.f, 0.f, 0.f, 0.f};

  // global->reg staging mappings
  const int arow = tid >> 2;            // 0..127
  const int ak8  = (tid & 3) << 3;      // 0,8,16,24
  const int gr   = row0 + arow;
  const int brow0 = tid >> 2;           // B granule 0 row
  const int bk8   = (tid & 3) << 3;

  // two named staging sets (rule: no runtime-indexed reg arrays)
  float4 aA0, aB0, aA1, aB1;            // CONVERT_A fp32 halves
  f16x8  hA0, hA1;                      // pre-f16 A
  f16x8  b0A, b0B, b1A, b1B;            // B granules (B unused if NB==1)

  const int nsteps = K >> 5;

#define LD_SET(kt, aA, aB, hA, bA, bB)                                         \
  {                                                                            \
    if constexpr (CONVERT_A) {                                                 \
      if (gr < M) {                                                            \
        const float* ap = Af32 + (size_t)gr * K + (kt) + ak8;                  \
        aA = *(const float4*)ap;                                               \
        aB = *(const float4*)(ap + 4);                                         \
      } else {                                                                 \
        aA = make_float4(0.f, 0.f, 0.f, 0.f);                                  \
        aB = make_float4(0.f, 0.f, 0.f, 0.f);                                  \
      }                                                                        \
    } else {                                                                   \
      if (gr < M) hA = *(const f16x8*)(A16 + (size_t)gr * K + (kt) + ak8);     \
      else        hA = (f16x8){0, 0, 0, 0, 0, 0, 0, 0};                        \
    }                                                                          \
    bA = *(const f16x8*)(Bt + (size_t)brow0 * K + (kt) + bk8);                 \
    if constexpr (NB > 1)                                                      \
      bB = *(const f16x8*)(Bt + (size_t)(brow0 + 128) * K + (kt) + bk8);       \
  }

#define WR_SET(buf, aA, aB, hA, bA, bB)                                        \
  {                                                                            \
    _Float16* as = As + (buf) * (BM * BK);                                     \
    _Float16* bs = Bs + (buf) * (BN * BK);                                     \
    if constexpr (CONVERT_A) {                                                 \
      f16x8 v;                                                                 \
      v[0] = (_Float16)aA.x; v[1] = (_Float16)aA.y;                            \
      v[2] = (_Float16)aA.z; v[3] = (_Float16)aA.w;                            \
      v[4] = (_Float16)aB.x; v[5] = (_Float16)aB.y;                            \
      v[6] = (_Float16)aB.z; v[7] = (_Float16)aB.w;                            \
      *(f16x8*)&as[arow * BK + ak8] = v;                                       \
    } else {                                                                   \
      *(f16x8*)&as[arow * BK + ak8] = hA;                                      \
    }                                                                          \
    *(f16x8*)&bs[brow0 * BK + bk8] = bA;                                       \
    if constexpr (NB > 1) *(f16x8*)&bs[(brow0 + 128) * BK + bk8] = bB;         \
  }

#define COMPUTE(buf)                                                           \
  {                                                                            \
    const _Float16* as = As + (buf) * (BM * BK);                               \
    const _Float16* bs = Bs + (buf) * (BN * BK);                               \
    f16x8 a[4], b[FN];                                                         \
    _Pragma("unroll")                                                          \
    for (int i = 0; i < 4; ++i)                                                \
      a[i] = *(const f16x8*)&as[(wm * 64 + i * 16 + l15) * BK + l16 * 8];      \
    _Pragma("unroll")                                                          \
    for (int j = 0; j < FN; ++j)                                               \
      b[j] = *(const f16x8*)&bs[(wn * (FN * 16) + j * 16 + l15) * BK + l16 * 8]; \
    _Pragma("unroll")                                                          \
    for (int i = 0; i < 4; ++i)                                                \
      _Pragma("unroll")                                                        \
      for (int j = 0; j < FN; ++j)                                             \
        acc[i][j] = __builtin_amdgcn_mfma_f32_16x16x32_f16(a[i], b[j], acc[i][j], 0, 0, 0); \
  }

  // prologue: set0 -> buf0 (one unavoidable vmcnt stall), prefetch step1 -> set1
  LD_SET(0, aA0, aB0, hA0, b0A, b0B);
  WR_SET(0, aA0, aB0, hA0, b0A, b0B);
  LD_SET(BK, aA1, aB1, hA1, b1A, b1B);
  __syncthreads();

  for (int tt = 0; tt < nsteps; tt += 2) {
    // even step t=tt: compute buf0; write(t+1)->buf1 from set1; load(t+2)->set0
    if (tt + 2 < nsteps) LD_SET((tt + 2) * BK, aA0, aB0, hA0, b0A, b0B);
    COMPUTE(0);
    if (tt + 1 < nsteps) WR_SET(1, aA1, aB1, hA1, b1A, b1B);
    __syncthreads();
    // odd step t=tt+1: compute buf1; write(t+2)->buf0 from set0; load(t+3)->set1
    if (tt + 1 < nsteps) {
      if (tt + 3 < nsteps) LD_SET((tt + 3) * BK, aA1, aB1, hA1, b1A, b1B);
      COMPUTE(1);
      if (tt + 2 < nsteps) WR_SET(0, aA0, aB0, hA0, b0A, b0B);
      __syncthreads();
    }
  }
#undef LD_SET
#undef WR_SET
#undef COMPUTE

  // ---------- epilogue: LDS-staged coalesced stores ----------
  constexpr int ESTR = BN + EPAD;
  constexpr int CPT  = BN / 16;
#pragma unroll
  for (int c = 0; c < 4; ++c) {
    if (wm == (c >> 1)) {
      const int ib = (c & 1) * 2;
#pragma unroll
      for (int ii = 0; ii < 2; ++ii) {
        const int i = ib + ii;
#pragma unroll
        for (int j = 0; j < FN; ++j) {
          const int col = wn * (FN * 16) + j * 16 + l15;
#pragma unroll
          for (int r = 0; r < 4; ++r) {
            const int lrow = ii * 16 + l16 * 4 + r;
            epi[lrow * ESTR + col] = acc[i][j][r];
          }
        }
      }
    }
    __syncthreads();
    {
      const int lrow = tid >> 4;
      const int grow = row0 + c * 32 + lrow;
      const int colb = (tid & 15) * CPT;
      if (grow < M) {
        float v[CPT];
#pragma unroll
        for (int q = 0; q < CPT; q += 4)
          *(float4*)&v[q] = *(const float4*)&epi[lrow * ESTR + colb + q];
        if constexpr (OUT_Y) {
          const float dv = dis[grow];
          f16x8 o[CPT / 8];
#pragma unroll
          for (int q = 0; q < CPT; ++q) o[q >> 3][q & 7] = (_Float16)(v[q] * dv);
#pragma unroll
          for (int q = 0; q < CPT / 8; ++q)
            *(f16x8*)(Y + (size_t)grow * BN + colb + q * 8) = o[q];
        } else {
#pragma unroll
          for (int q = 0; q < CPT; ++q) v[q] += bias[colb + q];
#pragma unroll
          for (int q = 0; q < CPT; q += 4)
            *(float4*)(C + (size_t)grow * BN + colb + q) = *(const float4*)&v[q];
        }
      }
    }
    __syncthreads();
  }
}

// ---------- gather-aggregate on pre-scaled f16 y-rows ----------
// out[v] = relu(dis[v] * (sum_{s in N(v)} y[s] + y[v]) + b); writes h f16.
// beg/end reconstructed as off[v] + bsum[v>>10] (scan3 eliminated).
__global__ __launch_bounds__(256) void gather_k(const _Float16* __restrict__ y,
                                                const int* __restrict__ ssorted,
                                                const int* __restrict__ off,
                                                const int* __restrict__ bsum,
                                                const float* __restrict__ dis,
                                                const float* __restrict__ bias,
                                                _Float16* __restrict__ h,
                                                int n, int E) {
  const int gid = blockIdx.x * 256 + threadIdx.x;
  const int v = gid >> 6, lane = gid & 63;
  if (v >= n) return;

  const float dv = dis[v];
  const int fo = lane * 4;

  f16x4 sv = *(const f16x4*)(y + (size_t)v * 256 + fo);  // self term y[v]
  float4 acc = make_float4((float)sv[0], (float)sv[1], (float)sv[2], (float)sv[3]);

  const int beg = off[v] + bsum[v >> 10];
  const int end = (v + 1 < n) ? (off[v + 1] + bsum[(v + 1) >> 10]) : E;
  const int ne = end - beg;

  for (int j0 = 0; j0 < ne; j0 += 64) {
    const int rem = ne - j0;
    const int cnt = rem < 64 ? rem : 64;
    int s_l = 0;
    if (lane < cnt) s_l = ssorted[beg + j0 + lane];

    int k = 0;
    for (; k + 8 <= cnt; k += 8) {
      f16x4 yv[8];
#pragma unroll
      for (int u = 0; u < 8; ++u) {
        const int s = __shfl(s_l, k + u);
        yv[u] = *(const f16x4*)(y + (size_t)s * 256 + fo);
      }
#pragma unroll
      for (int u = 0; u < 8; ++u) {
        acc.x += (float)yv[u][0];
        acc.y += (float)yv[u][1];
        acc.z += (float)yv[u][2];
        acc.w += (float)yv[u][3];
      }
    }
    for (; k < cnt; ++k) {
      const int s = __shfl(s_l, k);
      const f16x4 yv = *(const f16x4*)(y + (size_t)s * 256 + fo);
      acc.x += (float)yv[0];
      acc.y += (float)yv[1];
      acc.z += (float)yv[2];
      acc.w += (float)yv[3];
    }
  }

  const float4 b = *(const float4*)(bias + fo);
  f16x4 o;
  o[0] = (_Float16)fmaxf(fmaf(dv, acc.x, b.x), 0.f);
  o[1] = (_Float16)fmaxf(fmaf(dv, acc.y, b.y), 0.f);
  o[2] = (_Float16)fmaxf(fmaf(dv, acc.z, b.z), 0.f);
  o[3] = (_Float16)fmaxf(fmaf(dv, acc.w, b.w), 0.f);
  *(f16x4*)(h + (size_t)v * 256 + fo) = o;
}

// ---------- launch ----------
extern "C" void kernel_launch(void* const* d_in, const int* in_sizes, int n_in,
                              void* d_out, int out_size, void* d_ws, size_t ws_size,
                              hipStream_t stream) {
  const float* x    = (const float*)d_in[0];
  const int*   ei   = (const int*)d_in[1];
  const float* W1   = (const float*)d_in[2];
  const float* b1   = (const float*)d_in[3];
  const float* W2   = (const float*)d_in[4];
  const float* b2   = (const float*)d_in[5];
  const float* fc_w = (const float*)d_in[6];
  const float* fc_b = (const float*)d_in[7];
  float* out = (float*)d_out;

  const int E = in_sizes[1] / 2;
  const int* src = ei;
  const int* dst = ei + E;
  const int N = N_NODES;

  // workspace layout
  char* p = (char*)d_ws;
  int*   deg     = (int*)p;            p += (size_t)N * 4;
  float* dis     = (float*)p;          p += (size_t)N * 4;
  int*   off     = (int*)p;            p += (size_t)(N + 1) * 4;
  int*   pe      = (int*)p;            p += (size_t)E * 4;
  int*   ssorted = (int*)p;            p += (size_t)E * 4;
  int*   bsum    = (int*)p;            p += 512;
  p = (char*)(((size_t)p + 255) & ~(size_t)255);
  _Float16* w1t = (_Float16*)p;        p += (size_t)D_H   * D_IN * 2;
  _Float16* w2t = (_Float16*)p;        p += (size_t)D_H   * D_H  * 2;
  _Float16* fct = (_Float16*)p;        p += (size_t)D_OUT * D_H  * 2;
  p = (char*)(((size_t)p + 255) & ~(size_t)255);
  _Float16* y16 = (_Float16*)p;        p += (size_t)N * D_H * 2;  // 51.2 MB
  _Float16* h16 = (_Float16*)p;        p += (size_t)N * D_H * 2;  // 51.2 MB

  // weights (one kernel)
  wtrans_all_k<<<896, 256, 0, stream>>>(W1, W2, fc_w, w1t, w2t, fct);

  // CSR build (dis must precede layer-1 GEMM epilogue)
  const int NB1 = (N + 1023) / 1024;   // 98
  const int EB4 = ((E + 3) / 4 + 255) / 256;
  hipMemsetAsync(deg, 0, N * sizeof(int), stream);
  deg_count_k<<<EB4, 256, 0, stream>>>(dst, deg, pe, E);
  scan1_k<<<NB1, 256, 0, stream>>>(deg, off, bsum, dis, N);
  scan2_k<<<1, 128, 0, stream>>>(bsum, NB1);
  fill_k<<<EB4, 256, 0, stream>>>(src, dst, pe, off, bsum, ssorted, E);

  const int node_wave_blocks = (N * 64 + 255) / 256;
  const int MB = (N + 127) / 128;  // 782
  const dim3 gg(1, MB);

  // layer 1: y = dis * (x @ W1), f16
  gemm_pipe_k<256, true, true><<<gg, 512, 0, stream>>>(
      x, nullptr, w1t, nullptr, dis, nullptr, y16, N, D_IN);
  gather_k<<<node_wave_blocks, 256, 0, stream>>>(y16, ssorted, off, bsum, dis, b1, h16, N, E);

  // layer 2: y = dis * (h1 @ W2), f16
  gemm_pipe_k<256, false, true><<<gg, 512, 0, stream>>>(
      nullptr, h16, w2t, nullptr, dis, nullptr, y16, N, D_H);
  gather_k<<<node_wave_blocks, 256, 0, stream>>>(y16, ssorted, off, bsum, dis, b2, h16, N, E);

  // final fc: out = h2 @ fc_w + fc_b (fp32)
  gemm_pipe_k<128, false, false><<<gg, 512, 0, stream>>>(
      nullptr, h16, fct, fc_b, nullptr, out, nullptr, N, D_H);
}

// Round 9
// 505.437 us; speedup vs baseline: 22.5493x; 1.0283x over previous
//
#include <hip/hip_runtime.h>

// GCN on MI355X.
// R2: CSR gather. R3-R6: MFMA GEMM -> f16 1-term. R7/R8: reg-staged dbuf pipeline
// -- structurally capped: compiler drains vmcnt(0) at every barrier, so reg
// prefetch is 1-deep (gemm1 123us, MfmaUtil 8%).
// R9: T3 "minimum 2-phase" glds template: global_load_lds staging, dbuf LDS,
// stage(t+1) -> compute(t) -> ONE vmcnt+barrier per step. All GEMMs f16 (one-time
// x->f16 pass, buffers row-padded to 100096). Swizzle: linear LDS dest +
// inverse-swizzled global source + swizzled ds_read. EPAD back to 4.

#define N_NODES 100000
constexpr int D_IN  = 512;
constexpr int D_H   = 256;
constexpr int D_OUT = 128;
constexpr int M_PAD = 100096;   // 782*128

typedef _Float16 f16x8 __attribute__((ext_vector_type(8)));
typedef _Float16 f16x4 __attribute__((ext_vector_type(4)));
typedef float f32x4 __attribute__((ext_vector_type(4)));

#define GLD16(SRC, DST) __builtin_amdgcn_global_load_lds(                      \
    (const __attribute__((address_space(1))) void*)(SRC),                      \
    (__attribute__((address_space(3))) void*)(DST), 16, 0, 0)

// ---------- x -> f16 (pad rows zero-filled once per call; deterministic) ----------
__global__ __launch_bounds__(256) void cvt_x_k(const float* __restrict__ x,
                                               _Float16* __restrict__ x16) {
  size_t i = ((size_t)blockIdx.x * 256 + threadIdx.x) * 8;
  const size_t valid = (size_t)N_NODES * D_IN;
  if (i < valid) {
    float4 a = *(const float4*)(x + i);
    float4 b = *(const float4*)(x + i + 4);
    f16x8 v;
    v[0] = (_Float16)a.x; v[1] = (_Float16)a.y;
    v[2] = (_Float16)a.z; v[3] = (_Float16)a.w;
    v[4] = (_Float16)b.x; v[5] = (_Float16)b.y;
    v[6] = (_Float16)b.z; v[7] = (_Float16)b.w;
    *(f16x8*)(x16 + i) = v;
  } else if (i < (size_t)M_PAD * D_IN) {
    *(f16x8*)(x16 + i) = (f16x8){0, 0, 0, 0, 0, 0, 0, 0};
  }
}

// ---------- CSR build ----------
__global__ __launch_bounds__(256) void deg_count_k(const int* __restrict__ dst,
                                                   int* __restrict__ deg,
                                                   int* __restrict__ pe, int E) {
  int i = (blockIdx.x * 256 + threadIdx.x) * 4;
  if (i + 3 < E) {
    int4 d = *(const int4*)(dst + i);
    int4 p;
    p.x = atomicAdd(&deg[d.x], 1);
    p.y = atomicAdd(&deg[d.y], 1);
    p.z = atomicAdd(&deg[d.z], 1);
    p.w = atomicAdd(&deg[d.w], 1);
    *(int4*)(pe + i) = p;
  } else {
    for (int t = i; t < E; ++t) pe[t] = atomicAdd(&deg[dst[t]], 1);
  }
}

__global__ __launch_bounds__(256) void scan1_k(const int* __restrict__ deg,
                                               int* __restrict__ off,
                                               int* __restrict__ bsum,
                                               float* __restrict__ dis, int n) {
  __shared__ int ts[256];
  const int tid = threadIdx.x;
  const int base = blockIdx.x * 1024 + tid * 4;
  int v[4];
#pragma unroll
  for (int t = 0; t < 4; ++t) v[t] = (base + t < n) ? deg[base + t] : 0;
#pragma unroll
  for (int t = 0; t < 4; ++t)
    if (base + t < n) dis[base + t] = rsqrtf((float)v[t] + 1.0f);
  const int tot = v[0] + v[1] + v[2] + v[3];
  ts[tid] = tot;
  __syncthreads();
  for (int o = 1; o < 256; o <<= 1) {
    int t = (tid >= o) ? ts[tid - o] : 0;
    __syncthreads();
    ts[tid] += t;
    __syncthreads();
  }
  int run = ts[tid] - tot;
#pragma unroll
  for (int t = 0; t < 4; ++t) {
    if (base + t < n) off[base + t] = run;
    run += v[t];
  }
  if (tid == 255) bsum[blockIdx.x] = ts[255];
}

__global__ __launch_bounds__(128) void scan2_k(int* __restrict__ bsum, int nb) {
  __shared__ int ts[128];
  const int tid = threadIdx.x;
  const int v = (tid < nb) ? bsum[tid] : 0;
  ts[tid] = v;
  __syncthreads();
  for (int o = 1; o < 128; o <<= 1) {
    int t = (tid >= o) ? ts[tid - o] : 0;
    __syncthreads();
    ts[tid] += t;
    __syncthreads();
  }
  if (tid < nb) bsum[tid] = ts[tid] - v;
}

__global__ __launch_bounds__(256) void fill_k(const int* __restrict__ src,
                                              const int* __restrict__ dst,
                                              const int* __restrict__ pe,
                                              const int* __restrict__ off,
                                              const int* __restrict__ bsum,
                                              int* __restrict__ ssorted, int E) {
  int i = (blockIdx.x * 256 + threadIdx.x) * 4;
  if (i + 3 < E) {
    int4 s = *(const int4*)(src + i);
    int4 d = *(const int4*)(dst + i);
    int4 p = *(const int4*)(pe + i);
    ssorted[off[d.x] + bsum[d.x >> 10] + p.x] = s.x;
    ssorted[off[d.y] + bsum[d.y >> 10] + p.y] = s.y;
    ssorted[off[d.z] + bsum[d.z >> 10] + p.z] = s.z;
    ssorted[off[d.w] + bsum[d.w >> 10] + p.w] = s.w;
  } else {
    for (int t = i; t < E; ++t) {
      int d = dst[t];
      ssorted[off[d] + bsum[d >> 10] + pe[t]] = src[t];
    }
  }
}

// ---------- weight transposes (fp32 [K][N] -> f16 [N][K]) ----------
__global__ __launch_bounds__(256) void wtrans_all_k(const float* __restrict__ W1,
                                                    const float* __restrict__ W2,
                                                    const float* __restrict__ FC,
                                                    _Float16* __restrict__ w1t,
                                                    _Float16* __restrict__ w2t,
                                                    _Float16* __restrict__ fct) {
  int i = blockIdx.x * 256 + threadIdx.x;
  if (i < 131072) {                       // W1: 512x256
    int k = i >> 8, n = i & 255;
    w1t[(size_t)n * 512 + k] = (_Float16)W1[i];
  } else if (i < 196608) {                // W2: 256x256
    int j = i - 131072;
    int k = j >> 8, n = j & 255;
    w2t[(size_t)n * 256 + k] = (_Float16)W2[j];
  } else if (i < 229376) {                // fc_w: 256x128
    int j = i - 196608;
    int k = j >> 7, n = j & 127;
    fct[(size_t)n * 256 + k] = (_Float16)FC[j];
  }
}

// ---------- 2-phase glds f16 MFMA GEMM ----------
// C[M,BN] = A[M,K] @ Bt[BN,K]^T. grid=(1, M_PAD/128). BM=128, BK=32, 512 thr =
// 8 waves (2x4), per-wave 64x(16*FN). Dbuf LDS staged by global_load_lds
// (3 instrs/wave/step); stage(t+1) -> ds_read+MFMA(t) -> __syncthreads (vmcnt
// drain = the only wait). Source granule pre-swizzled (g ^= row&3), read with
// same XOR. A rows must be padded to M_PAD (OOB-safe).
// OUT_Y: Y = dis[row]*(A@B) f16. else: C = A@B + bias, fp32.
template<int BN, bool OUT_Y>
__global__ __launch_bounds__(512, 4) void gemm_glds_k(
    const _Float16* __restrict__ A16,
    const _Float16* __restrict__ Bt,
    const float* __restrict__ bias,
    const float* __restrict__ dis,
    float* __restrict__ C,
    _Float16* __restrict__ Y,
    int M, int K) {
  constexpr int BM = 128, BK = 32;
  constexpr int FN  = BN / 64;        // 4 (BN=256) or 2 (BN=128)
  constexpr int NBI = BN / 128;       // B glds instrs per wave (2 or 1)
  constexpr int ASZ = BM * BK;        // f16 per buffer
  constexpr int BSZ = BN * BK;
  constexpr int EPAD = 4;

  __shared__ __align__(16) _Float16 smem[2 * (ASZ + BSZ)];  // 48 KB (BN=256)
  _Float16* As = smem;                 // [2][ASZ]
  _Float16* Bs = smem + 2 * ASZ;       // [2][BSZ]
  float* epi = (float*)smem;           // reused after K-loop

  const int tid  = threadIdx.x;
  const int w    = tid >> 6, lane = tid & 63;
  const int wm   = w >> 2, wn = w & 3;
  const int l15  = lane & 15, l16 = lane >> 4;
  const int row0 = blockIdx.y * BM;

  // glds lane mapping: each instr = 16 rows x 64B; lane l -> row l>>2, slot l&3
  const int lr = lane >> 2, lg = lane & 3;
  const int arow  = w * 16 + lr;                    // LDS A row 0..127
  const int brow0 = w * (NBI * 16) + lr;            // LDS B row
  const int brow1 = brow0 + 16;
  const _Float16* srcA  = A16 + (size_t)(row0 + arow) * K + ((lg ^ (arow & 3)) << 3);
  const _Float16* srcB0 = Bt + (size_t)brow0 * K + ((lg ^ (brow0 & 3)) << 3);
  const _Float16* srcB1 = Bt + (size_t)brow1 * K + ((lg ^ (brow1 & 3)) << 3);
  _Float16* dstA  = &As[(w * 16) * BK];             // wave-uniform bases
  _Float16* dstB0 = &Bs[(w * (NBI * 16)) * BK];
  _Float16* dstB1 = &Bs[(w * (NBI * 16) + 16) * BK];

  f32x4 acc[4][FN];
#pragma unroll
  for (int i = 0; i < 4; ++i)
#pragma unroll
    for (int j = 0; j < FN; ++j) acc[i][j] = (f32x4){0.f, 0.f, 0.f, 0.f};

  const int nsteps = K >> 5;

  auto stage = [&](int t) {
    const int kt = t << 5;
    const int pa = (t & 1) * ASZ, pb = (t & 1) * BSZ;
    GLD16(srcA + kt, dstA + pa);
    GLD16(srcB0 + kt, dstB0 + pb);
    if constexpr (NBI == 2) GLD16(srcB1 + kt, dstB1 + pb);
  };

  stage(0);
  __syncthreads();                     // vmcnt drained by compiler before barrier

  for (int t = 0; t < nsteps; ++t) {
    if (t + 1 < nsteps) stage(t + 1);  // lands in other buffer; drained at barrier
    const _Float16* as = As + (t & 1) * ASZ;
    const _Float16* bs = Bs + (t & 1) * BSZ;
    f16x8 a[4], b[FN];
#pragma unroll
    for (int i = 0; i < 4; ++i) {
      const int r = wm * 64 + i * 16 + l15;
      a[i] = *(const f16x8*)&as[r * BK + ((l16 ^ (r & 3)) << 3)];
    }
#pragma unroll
    for (int j = 0; j < FN; ++j) {
      const int n = wn * (FN * 16) + j * 16 + l15;
      b[j] = *(const f16x8*)&bs[n * BK + ((l16 ^ (n & 3)) << 3)];
    }
#pragma unroll
    for (int i = 0; i < 4; ++i)
#pragma unroll
      for (int j = 0; j < FN; ++j)
        acc[i][j] = __builtin_amdgcn_mfma_f32_16x16x32_f16(a[i], b[j], acc[i][j], 0, 0, 0);
    __syncthreads();
  }

  // ---------- epilogue: LDS-staged coalesced stores (EPAD=4) ----------
  constexpr int ESTR = BN + EPAD;
  constexpr int CPT  = BN / 16;
#pragma unroll
  for (int c = 0; c < 4; ++c) {
    if (wm == (c >> 1)) {
      const int ib = (c & 1) * 2;
#pragma unroll
      for (int ii = 0; ii < 2; ++ii) {
        const int i = ib + ii;
#pragma unroll
        for (int j = 0; j < FN; ++j) {
          const int col = wn * (FN * 16) + j * 16 + l15;
#pragma unroll
          for (int r = 0; r < 4; ++r) {
            const int lrow = ii * 16 + l16 * 4 + r;
            epi[lrow * ESTR + col] = acc[i][j][r];
          }
        }
      }
    }
    __syncthreads();
    {
      const int lrow = tid >> 4;
      const int grow = row0 + c * 32 + lrow;
      const int colb = (tid & 15) * CPT;
      if (grow < M) {
        float v[CPT];
#pragma unroll
        for (int q = 0; q < CPT; q += 4)
          *(float4*)&v[q] = *(const float4*)&epi[lrow * ESTR + colb + q];
        if constexpr (OUT_Y) {
          const float dv = dis[grow];
          f16x8 o[CPT / 8];
#pragma unroll
          for (int q = 0; q < CPT; ++q) o[q >> 3][q & 7] = (_Float16)(v[q] * dv);
#pragma unroll
          for (int q = 0; q < CPT / 8; ++q)
            *(f16x8*)(Y + (size_t)grow * BN + colb + q * 8) = o[q];
        } else {
#pragma unroll
          for (int q = 0; q < CPT; ++q) v[q] += bias[colb + q];
#pragma unroll
          for (int q = 0; q < CPT; q += 4)
            *(float4*)(C + (size_t)grow * BN + colb + q) = *(const float4*)&v[q];
        }
      }
    }
    __syncthreads();
  }
}

// ---------- gather-aggregate on pre-scaled f16 y-rows ----------
__global__ __launch_bounds__(256) void gather_k(const _Float16* __restrict__ y,
                                                const int* __restrict__ ssorted,
                                                const int* __restrict__ off,
                                                const int* __restrict__ bsum,
                                                const float* __restrict__ dis,
                                                const float* __restrict__ bias,
                                                _Float16* __restrict__ h,
                                                int n, int E) {
  const int gid = blockIdx.x * 256 + threadIdx.x;
  const int v = gid >> 6, lane = gid & 63;
  if (v >= n) return;

  const float dv = dis[v];
  const int fo = lane * 4;

  f16x4 sv = *(const f16x4*)(y + (size_t)v * 256 + fo);  // self term y[v]
  float4 acc = make_float4((float)sv[0], (float)sv[1], (float)sv[2], (float)sv[3]);

  const int beg = off[v] + bsum[v >> 10];
  const int end = (v + 1 < n) ? (off[v + 1] + bsum[(v + 1) >> 10]) : E;
  const int ne = end - beg;

  for (int j0 = 0; j0 < ne; j0 += 64) {
    const int rem = ne - j0;
    const int cnt = rem < 64 ? rem : 64;
    int s_l = 0;
    if (lane < cnt) s_l = ssorted[beg + j0 + lane];

    int k = 0;
    for (; k + 8 <= cnt; k += 8) {
      f16x4 yv[8];
#pragma unroll
      for (int u = 0; u < 8; ++u) {
        const int s = __shfl(s_l, k + u);
        yv[u] = *(const f16x4*)(y + (size_t)s * 256 + fo);
      }
#pragma unroll
      for (int u = 0; u < 8; ++u) {
        acc.x += (float)yv[u][0];
        acc.y += (float)yv[u][1];
        acc.z += (float)yv[u][2];
        acc.w += (float)yv[u][3];
      }
    }
    for (; k < cnt; ++k) {
      const int s = __shfl(s_l, k);
      const f16x4 yv = *(const f16x4*)(y + (size_t)s * 256 + fo);
      acc.x += (float)yv[0];
      acc.y += (float)yv[1];
      acc.z += (float)yv[2];
      acc.w += (float)yv[3];
    }
  }

  const float4 b = *(const float4*)(bias + fo);
  f16x4 o;
  o[0] = (_Float16)fmaxf(fmaf(dv, acc.x, b.x), 0.f);
  o[1] = (_Float16)fmaxf(fmaf(dv, acc.y, b.y), 0.f);
  o[2] = (_Float16)fmaxf(fmaf(dv, acc.z, b.z), 0.f);
  o[3] = (_Float16)fmaxf(fmaf(dv, acc.w, b.w), 0.f);
  *(f16x4*)(h + (size_t)v * 256 + fo) = o;
}

// ---------- launch ----------
extern "C" void kernel_launch(void* const* d_in, const int* in_sizes, int n_in,
                              void* d_out, int out_size, void* d_ws, size_t ws_size,
                              hipStream_t stream) {
  const float* x    = (const float*)d_in[0];
  const int*   ei   = (const int*)d_in[1];
  const float* W1   = (const float*)d_in[2];
  const float* b1   = (const float*)d_in[3];
  const float* W2   = (const float*)d_in[4];
  const float* b2   = (const float*)d_in[5];
  const float* fc_w = (const float*)d_in[6];
  const float* fc_b = (const float*)d_in[7];
  float* out = (float*)d_out;

  const int E = in_sizes[1] / 2;
  const int* src = ei;
  const int* dst = ei + E;
  const int N = N_NODES;

  // workspace layout (~219 MB)
  char* p = (char*)d_ws;
  int*   deg     = (int*)p;            p += (size_t)N * 4;
  float* dis     = (float*)p;          p += (size_t)N * 4;
  int*   off     = (int*)p;            p += (size_t)(N + 1) * 4;
  int*   pe      = (int*)p;            p += (size_t)E * 4;
  int*   ssorted = (int*)p;            p += (size_t)E * 4;
  int*   bsum    = (int*)p;            p += 512;
  p = (char*)(((size_t)p + 255) & ~(size_t)255);
  _Float16* w1t = (_Float16*)p;        p += (size_t)D_H   * D_IN * 2;
  _Float16* w2t = (_Float16*)p;        p += (size_t)D_H   * D_H  * 2;
  _Float16* fct = (_Float16*)p;        p += (size_t)D_OUT * D_H  * 2;
  p = (char*)(((size_t)p + 255) & ~(size_t)255);
  _Float16* x16 = (_Float16*)p;        p += (size_t)M_PAD * D_IN * 2;  // 102.5 MB
  _Float16* y16 = (_Float16*)p;        p += (size_t)M_PAD * D_H * 2;   // 51.25 MB
  _Float16* h16 = (_Float16*)p;        p += (size_t)M_PAD * D_H * 2;   // 51.25 MB

  // x -> f16 (padded), weights
  cvt_x_k<<<(M_PAD * (D_IN / 8) + 255) / 256, 256, 0, stream>>>(x, x16);
  wtrans_all_k<<<896, 256, 0, stream>>>(W1, W2, fc_w, w1t, w2t, fct);

  // CSR build
  const int NB1 = (N + 1023) / 1024;   // 98
  const int EB4 = ((E + 3) / 4 + 255) / 256;
  hipMemsetAsync(deg, 0, N * sizeof(int), stream);
  deg_count_k<<<EB4, 256, 0, stream>>>(dst, deg, pe, E);
  scan1_k<<<NB1, 256, 0, stream>>>(deg, off, bsum, dis, N);
  scan2_k<<<1, 128, 0, stream>>>(bsum, NB1);
  fill_k<<<EB4, 256, 0, stream>>>(src, dst, pe, off, bsum, ssorted, E);

  const int node_wave_blocks = (N * 64 + 255) / 256;
  const dim3 gg(1, M_PAD / 128);  // 782

  // layer 1: y = dis * (x @ W1), f16
  gemm_glds_k<256, true><<<gg, 512, 0, stream>>>(
      x16, w1t, nullptr, dis, nullptr, y16, N, D_IN);
  gather_k<<<node_wave_blocks, 256, 0, stream>>>(y16, ssorted, off, bsum, dis, b1, h16, N, E);

  // layer 2: y = dis * (h1 @ W2), f16
  gemm_glds_k<256, true><<<gg, 512, 0, stream>>>(
      h16, w2t, nullptr, dis, nullptr, y16, N, D_H);
  gather_k<<<node_wave_blocks, 256, 0, stream>>>(y16, ssorted, off, bsum, dis, b2, h16, N, E);

  // final fc: out = h2 @ fc_w + fc_b (fp32)
  gemm_glds_k<128, false><<<gg, 512, 0, stream>>>(
      h16, fct, fc_b, nullptr, out, nullptr, N, D_H);
}

// Round 10
// 500.742 us; speedup vs baseline: 22.7607x; 1.0094x over previous
//
#include <hip/hip_runtime.h>

// GCN on MI355X.
// R2: CSR gather. R3-R8: MFMA GEMM evolution; reg-staged pipelines capped by
// vmcnt(0)-at-barrier. R9: glds 2-phase dbuf (gemm1 ~75us). Gathers at their
// bytes floor (119us each, 819MB logical @6.9TB/s effective).
// R10: T4 counted vmcnt + TRIPLE-buffered glds staging: 2 stages in flight,
// s_waitcnt vmcnt(3) + raw s_barrier per step (never drain to 0 in-loop).
// LDS 72KB -> still 2 blocks/CU.

#define N_NODES 100000
constexpr int D_IN  = 512;
constexpr int D_H   = 256;
constexpr int D_OUT = 128;
constexpr int M_PAD = 100096;   // 782*128

typedef _Float16 f16x8 __attribute__((ext_vector_type(8)));
typedef _Float16 f16x4 __attribute__((ext_vector_type(4)));
typedef float f32x4 __attribute__((ext_vector_type(4)));

#define GLD16(SRC, DST) __builtin_amdgcn_global_load_lds(                      \
    (const __attribute__((address_space(1))) void*)(SRC),                      \
    (__attribute__((address_space(3))) void*)(DST), 16, 0, 0)

// ---------- x -> f16 (pad rows zero-filled; deterministic each call) ----------
__global__ __launch_bounds__(256) void cvt_x_k(const float* __restrict__ x,
                                               _Float16* __restrict__ x16) {
  size_t i = ((size_t)blockIdx.x * 256 + threadIdx.x) * 8;
  const size_t valid = (size_t)N_NODES * D_IN;
  if (i < valid) {
    float4 a = *(const float4*)(x + i);
    float4 b = *(const float4*)(x + i + 4);
    f16x8 v;
    v[0] = (_Float16)a.x; v[1] = (_Float16)a.y;
    v[2] = (_Float16)a.z; v[3] = (_Float16)a.w;
    v[4] = (_Float16)b.x; v[5] = (_Float16)b.y;
    v[6] = (_Float16)b.z; v[7] = (_Float16)b.w;
    *(f16x8*)(x16 + i) = v;
  } else if (i < (size_t)M_PAD * D_IN) {
    *(f16x8*)(x16 + i) = (f16x8){0, 0, 0, 0, 0, 0, 0, 0};
  }
}

// ---------- CSR build ----------
__global__ __launch_bounds__(256) void deg_count_k(const int* __restrict__ dst,
                                                   int* __restrict__ deg,
                                                   int* __restrict__ pe, int E) {
  int i = (blockIdx.x * 256 + threadIdx.x) * 4;
  if (i + 3 < E) {
    int4 d = *(const int4*)(dst + i);
    int4 p;
    p.x = atomicAdd(&deg[d.x], 1);
    p.y = atomicAdd(&deg[d.y], 1);
    p.z = atomicAdd(&deg[d.z], 1);
    p.w = atomicAdd(&deg[d.w], 1);
    *(int4*)(pe + i) = p;
  } else {
    for (int t = i; t < E; ++t) pe[t] = atomicAdd(&deg[dst[t]], 1);
  }
}

__global__ __launch_bounds__(256) void scan1_k(const int* __restrict__ deg,
                                               int* __restrict__ off,
                                               int* __restrict__ bsum,
                                               float* __restrict__ dis, int n) {
  __shared__ int ts[256];
  const int tid = threadIdx.x;
  const int base = blockIdx.x * 1024 + tid * 4;
  int v[4];
#pragma unroll
  for (int t = 0; t < 4; ++t) v[t] = (base + t < n) ? deg[base + t] : 0;
#pragma unroll
  for (int t = 0; t < 4; ++t)
    if (base + t < n) dis[base + t] = rsqrtf((float)v[t] + 1.0f);
  const int tot = v[0] + v[1] + v[2] + v[3];
  ts[tid] = tot;
  __syncthreads();
  for (int o = 1; o < 256; o <<= 1) {
    int t = (tid >= o) ? ts[tid - o] : 0;
    __syncthreads();
    ts[tid] += t;
    __syncthreads();
  }
  int run = ts[tid] - tot;
#pragma unroll
  for (int t = 0; t < 4; ++t) {
    if (base + t < n) off[base + t] = run;
    run += v[t];
  }
  if (tid == 255) bsum[blockIdx.x] = ts[255];
}

__global__ __launch_bounds__(128) void scan2_k(int* __restrict__ bsum, int nb) {
  __shared__ int ts[128];
  const int tid = threadIdx.x;
  const int v = (tid < nb) ? bsum[tid] : 0;
  ts[tid] = v;
  __syncthreads();
  for (int o = 1; o < 128; o <<= 1) {
    int t = (tid >= o) ? ts[tid - o] : 0;
    __syncthreads();
    ts[tid] += t;
    __syncthreads();
  }
  if (tid < nb) bsum[tid] = ts[tid] - v;
}

__global__ __launch_bounds__(256) void fill_k(const int* __restrict__ src,
                                              const int* __restrict__ dst,
                                              const int* __restrict__ pe,
                                              const int* __restrict__ off,
                                              const int* __restrict__ bsum,
                                              int* __restrict__ ssorted, int E) {
  int i = (blockIdx.x * 256 + threadIdx.x) * 4;
  if (i + 3 < E) {
    int4 s = *(const int4*)(src + i);
    int4 d = *(const int4*)(dst + i);
    int4 p = *(const int4*)(pe + i);
    ssorted[off[d.x] + bsum[d.x >> 10] + p.x] = s.x;
    ssorted[off[d.y] + bsum[d.y >> 10] + p.y] = s.y;
    ssorted[off[d.z] + bsum[d.z >> 10] + p.z] = s.z;
    ssorted[off[d.w] + bsum[d.w >> 10] + p.w] = s.w;
  } else {
    for (int t = i; t < E; ++t) {
      int d = dst[t];
      ssorted[off[d] + bsum[d >> 10] + pe[t]] = src[t];
    }
  }
}

// ---------- weight transposes (fp32 [K][N] -> f16 [N][K]) ----------
__global__ __launch_bounds__(256) void wtrans_all_k(const float* __restrict__ W1,
                                                    const float* __restrict__ W2,
                                                    const float* __restrict__ FC,
                                                    _Float16* __restrict__ w1t,
                                                    _Float16* __restrict__ w2t,
                                                    _Float16* __restrict__ fct) {
  int i = blockIdx.x * 256 + threadIdx.x;
  if (i < 131072) {                       // W1: 512x256
    int k = i >> 8, n = i & 255;
    w1t[(size_t)n * 512 + k] = (_Float16)W1[i];
  } else if (i < 196608) {                // W2: 256x256
    int j = i - 131072;
    int k = j >> 8, n = j & 255;
    w2t[(size_t)n * 256 + k] = (_Float16)W2[j];
  } else if (i < 229376) {                // fc_w: 256x128
    int j = i - 196608;
    int k = j >> 7, n = j & 127;
    fct[(size_t)n * 256 + k] = (_Float16)FC[j];
  }
}

// ---------- triple-buffered glds f16 MFMA GEMM, counted vmcnt ----------
// C[M,BN] = A[M,K] @ Bt[BN,K]^T. grid=(1, M_PAD/128). BM=128, BK=32, 512 thr =
// 8 waves (2x4). Pipeline: stage(0),stage(1) in prologue; per step t:
//   s_waitcnt vmcnt(STAGE_INSTRS)  [stage(t) landed, stage(t+1) in flight]
//   s_barrier                      [all waves' stage(t) landed; buf (t-1)%3 free]
//   stage(t+2) -> buf (t+2)%3      [the freed buffer]
//   ds_read + MFMA on buf t%3
// Loads never drain to 0 inside the loop (T4, m218). sched_barrier fences (rule 18).
// OUT_Y: Y = dis[row]*(A@B) f16. else: C = A@B + bias, fp32.
template<int BN, bool OUT_Y>
__global__ __launch_bounds__(512, 4) void gemm_glds_k(
    const _Float16* __restrict__ A16,
    const _Float16* __restrict__ Bt,
    const float* __restrict__ bias,
    const float* __restrict__ dis,
    float* __restrict__ C,
    _Float16* __restrict__ Y,
    int M, int K) {
  constexpr int BM = 128, BK = 32;
  constexpr int FN  = BN / 64;        // 4 (BN=256) or 2 (BN=128)
  constexpr int NBI = BN / 128;       // B glds instrs per wave (2 or 1)
  constexpr int ASZ = BM * BK;        // f16 per buffer
  constexpr int BSZ = BN * BK;
  constexpr int EPAD = 4;

  __shared__ __align__(16) _Float16 smem[3 * (ASZ + BSZ)];  // 72 KB (BN=256)
  _Float16* As = smem;                 // [3][ASZ]
  _Float16* Bs = smem + 3 * ASZ;       // [3][BSZ]
  float* epi = (float*)smem;           // reused after K-loop

  const int tid  = threadIdx.x;
  const int w    = tid >> 6, lane = tid & 63;
  const int wm   = w >> 2, wn = w & 3;
  const int l15  = lane & 15, l16 = lane >> 4;
  const int row0 = blockIdx.y * BM;

  // glds lane mapping: each instr = 16 rows x 64B; lane l -> row l>>2, slot l&3
  const int lr = lane >> 2, lg = lane & 3;
  const int arow  = w * 16 + lr;
  const int brow0 = w * (NBI * 16) + lr;
  const int brow1 = brow0 + 16;
  const _Float16* srcA  = A16 + (size_t)(row0 + arow) * K + ((lg ^ (arow & 3)) << 3);
  const _Float16* srcB0 = Bt + (size_t)brow0 * K + ((lg ^ (brow0 & 3)) << 3);
  const _Float16* srcB1 = Bt + (size_t)brow1 * K + ((lg ^ (brow1 & 3)) << 3);
  _Float16* dstA  = &As[(w * 16) * BK];
  _Float16* dstB0 = &Bs[(w * (NBI * 16)) * BK];
  _Float16* dstB1 = &Bs[(w * (NBI * 16) + 16) * BK];

  f32x4 acc[4][FN];
#pragma unroll
  for (int i = 0; i < 4; ++i)
#pragma unroll
    for (int j = 0; j < FN; ++j) acc[i][j] = (f32x4){0.f, 0.f, 0.f, 0.f};

  const int nsteps = K >> 5;

  auto stage = [&](int t, int buf) {
    const int kt = t << 5;
    GLD16(srcA + kt, dstA + buf * ASZ);
    GLD16(srcB0 + kt, dstB0 + buf * BSZ);
    if constexpr (NBI == 2) GLD16(srcB1 + kt, dstB1 + buf * BSZ);
  };

  // prologue: two stages in flight
  stage(0, 0);
  if (nsteps > 1) stage(1, 1);

  int rbuf = 0;        // buffer for compute(t)
  int wbuf = 2;        // buffer for stage(t+2)
  for (int t = 0; t < nsteps; ++t) {
    if (t + 1 < nsteps) {
      // wait for stage(t) only; stage(t+1)'s loads stay in flight
      if constexpr (NBI == 2) asm volatile("s_waitcnt vmcnt(3)" ::: "memory");
      else                    asm volatile("s_waitcnt vmcnt(2)" ::: "memory");
    } else {
      asm volatile("s_waitcnt vmcnt(0)" ::: "memory");
    }
    __builtin_amdgcn_sched_barrier(0);
    __builtin_amdgcn_s_barrier();
    __builtin_amdgcn_sched_barrier(0);

    if (t + 2 < nsteps) stage(t + 2, wbuf);   // freed by the barrier above

    const _Float16* as = As + rbuf * ASZ;
    const _Float16* bs = Bs + rbuf * BSZ;
    f16x8 a[4], b[FN];
#pragma unroll
    for (int i = 0; i < 4; ++i) {
      const int r = wm * 64 + i * 16 + l15;
      a[i] = *(const f16x8*)&as[r * BK + ((l16 ^ (r & 3)) << 3)];
    }
#pragma unroll
    for (int j = 0; j < FN; ++j) {
      const int n = wn * (FN * 16) + j * 16 + l15;
      b[j] = *(const f16x8*)&bs[n * BK + ((l16 ^ (n & 3)) << 3)];
    }
#pragma unroll
    for (int i = 0; i < 4; ++i)
#pragma unroll
      for (int j = 0; j < FN; ++j)
        acc[i][j] = __builtin_amdgcn_mfma_f32_16x16x32_f16(a[i], b[j], acc[i][j], 0, 0, 0);

    rbuf = (rbuf == 2) ? 0 : rbuf + 1;
    wbuf = (wbuf == 2) ? 0 : wbuf + 1;
  }
  __syncthreads();   // all waves done reading stage LDS before epi reuse

  // ---------- epilogue: LDS-staged coalesced stores ----------
  constexpr int ESTR = BN + EPAD;
  constexpr int CPT  = BN / 16;
#pragma unroll
  for (int c = 0; c < 4; ++c) {
    if (wm == (c >> 1)) {
      const int ib = (c & 1) * 2;
#pragma unroll
      for (int ii = 0; ii < 2; ++ii) {
        const int i = ib + ii;
#pragma unroll
        for (int j = 0; j < FN; ++j) {
          const int col = wn * (FN * 16) + j * 16 + l15;
#pragma unroll
          for (int r = 0; r < 4; ++r) {
            const int lrow = ii * 16 + l16 * 4 + r;
            epi[lrow * ESTR + col] = acc[i][j][r];
          }
        }
      }
    }
    __syncthreads();
    {
      const int lrow = tid >> 4;
      const int grow = row0 + c * 32 + lrow;
      const int colb = (tid & 15) * CPT;
      if (grow < M) {
        float v[CPT];
#pragma unroll
        for (int q = 0; q < CPT; q += 4)
          *(float4*)&v[q] = *(const float4*)&epi[lrow * ESTR + colb + q];
        if constexpr (OUT_Y) {
          const float dv = dis[grow];
          f16x8 o[CPT / 8];
#pragma unroll
          for (int q = 0; q < CPT; ++q) o[q >> 3][q & 7] = (_Float16)(v[q] * dv);
#pragma unroll
          for (int q = 0; q < CPT / 8; ++q)
            *(f16x8*)(Y + (size_t)grow * BN + colb + q * 8) = o[q];
        } else {
#pragma unroll
          for (int q = 0; q < CPT; ++q) v[q] += bias[colb + q];
#pragma unroll
          for (int q = 0; q < CPT; q += 4)
            *(float4*)(C + (size_t)grow * BN + colb + q) = *(const float4*)&v[q];
        }
      }
    }
    __syncthreads();
  }
}

// ---------- gather-aggregate on pre-scaled f16 y-rows ----------
__global__ __launch_bounds__(256) void gather_k(const _Float16* __restrict__ y,
                                                const int* __restrict__ ssorted,
                                                const int* __restrict__ off,
                                                const int* __restrict__ bsum,
                                                const float* __restrict__ dis,
                                                const float* __restrict__ bias,
                                                _Float16* __restrict__ h,
                                                int n, int E) {
  const int gid = blockIdx.x * 256 + threadIdx.x;
  const int v = gid >> 6, lane = gid & 63;
  if (v >= n) return;

  const float dv = dis[v];
  const int fo = lane * 4;

  f16x4 sv = *(const f16x4*)(y + (size_t)v * 256 + fo);  // self term y[v]
  float4 acc = make_float4((float)sv[0], (float)sv[1], (float)sv[2], (float)sv[3]);

  const int beg = off[v] + bsum[v >> 10];
  const int end = (v + 1 < n) ? (off[v + 1] + bsum[(v + 1) >> 10]) : E;
  const int ne = end - beg;

  for (int j0 = 0; j0 < ne; j0 += 64) {
    const int rem = ne - j0;
    const int cnt = rem < 64 ? rem : 64;
    int s_l = 0;
    if (lane < cnt) s_l = ssorted[beg + j0 + lane];

    int k = 0;
    for (; k + 8 <= cnt; k += 8) {
      f16x4 yv[8];
#pragma unroll
      for (int u = 0; u < 8; ++u) {
        const int s = __shfl(s_l, k + u);
        yv[u] = *(const f16x4*)(y + (size_t)s * 256 + fo);
      }
#pragma unroll
      for (int u = 0; u < 8; ++u) {
        acc.x += (float)yv[u][0];
        acc.y += (float)yv[u][1];
        acc.z += (float)yv[u][2];
        acc.w += (float)yv[u][3];
      }
    }
    for (; k < cnt; ++k) {
      const int s = __shfl(s_l, k);
      const f16x4 yv = *(const f16x4*)(y + (size_t)s * 256 + fo);
      acc.x += (float)yv[0];
      acc.y += (float)yv[1];
      acc.z += (float)yv[2];
      acc.w += (float)yv[3];
    }
  }

  const float4 b = *(const float4*)(bias + fo);
  f16x4 o;
  o[0] = (_Float16)fmaxf(fmaf(dv, acc.x, b.x), 0.f);
  o[1] = (_Float16)fmaxf(fmaf(dv, acc.y, b.y), 0.f);
  o[2] = (_Float16)fmaxf(fmaf(dv, acc.z, b.z), 0.f);
  o[3] = (_Float16)fmaxf(fmaf(dv, acc.w, b.w), 0.f);
  *(f16x4*)(h + (size_t)v * 256 + fo) = o;
}

// ---------- launch ----------
extern "C" void kernel_launch(void* const* d_in, const int* in_sizes, int n_in,
                              void* d_out, int out_size, void* d_ws, size_t ws_size,
                              hipStream_t stream) {
  const float* x    = (const float*)d_in[0];
  const int*   ei   = (const int*)d_in[1];
  const float* W1   = (const float*)d_in[2];
  const float* b1   = (const float*)d_in[3];
  const float* W2   = (const float*)d_in[4];
  const float* b2   = (const float*)d_in[5];
  const float* fc_w = (const float*)d_in[6];
  const float* fc_b = (const float*)d_in[7];
  float* out = (float*)d_out;

  const int E = in_sizes[1] / 2;
  const int* src = ei;
  const int* dst = ei + E;
  const int N = N_NODES;

  // workspace layout (~219 MB)
  char* p = (char*)d_ws;
  int*   deg     = (int*)p;            p += (size_t)N * 4;
  float* dis     = (float*)p;          p += (size_t)N * 4;
  int*   off     = (int*)p;            p += (size_t)(N + 1) * 4;
  int*   pe      = (int*)p;            p += (size_t)E * 4;
  int*   ssorted = (int*)p;            p += (size_t)E * 4;
  int*   bsum    = (int*)p;            p += 512;
  p = (char*)(((size_t)p + 255) & ~(size_t)255);
  _Float16* w1t = (_Float16*)p;        p += (size_t)D_H   * D_IN * 2;
  _Float16* w2t = (_Float16*)p;        p += (size_t)D_H   * D_H  * 2;
  _Float16* fct = (_Float16*)p;        p += (size_t)D_OUT * D_H  * 2;
  p = (char*)(((size_t)p + 255) & ~(size_t)255);
  _Float16* x16 = (_Float16*)p;        p += (size_t)M_PAD * D_IN * 2;  // 102.5 MB
  _Float16* y16 = (_Float16*)p;        p += (size_t)M_PAD * D_H * 2;   // 51.25 MB
  _Float16* h16 = (_Float16*)p;        p += (size_t)M_PAD * D_H * 2;   // 51.25 MB

  // x -> f16 (padded), weights
  cvt_x_k<<<(M_PAD * (D_IN / 8) + 255) / 256, 256, 0, stream>>>(x, x16);
  wtrans_all_k<<<896, 256, 0, stream>>>(W1, W2, fc_w, w1t, w2t, fct);

  // CSR build
  const int NB1 = (N + 1023) / 1024;   // 98
  const int EB4 = ((E + 3) / 4 + 255) / 256;
  hipMemsetAsync(deg, 0, N * sizeof(int), stream);
  deg_count_k<<<EB4, 256, 0, stream>>>(dst, deg, pe, E);
  scan1_k<<<NB1, 256, 0, stream>>>(deg, off, bsum, dis, N);
  scan2_k<<<1, 128, 0, stream>>>(bsum, NB1);
  fill_k<<<EB4, 256, 0, stream>>>(src, dst, pe, off, bsum, ssorted, E);

  const int node_wave_blocks = (N * 64 + 255) / 256;
  const dim3 gg(1, M_PAD / 128);  // 782

  // layer 1: y = dis * (x @ W1), f16
  gemm_glds_k<256, true><<<gg, 512, 0, stream>>>(
      x16, w1t, nullptr, dis, nullptr, y16, N, D_IN);
  gather_k<<<node_wave_blocks, 256, 0, stream>>>(y16, ssorted, off, bsum, dis, b1, h16, N, E);

  // layer 2: y = dis * (h1 @ W2), f16
  gemm_glds_k<256, true><<<gg, 512, 0, stream>>>(
      h16, w2t, nullptr, dis, nullptr, y16, N, D_H);
  gather_k<<<node_wave_blocks, 256, 0, stream>>>(y16, ssorted, off, bsum, dis, b2, h16, N, E);

  // final fc: out = h2 @ fc_w + fc_b (fp32)
  gemm_glds_k<128, false><<<gg, 512, 0, stream>>>(
      h16, fct, fc_b, nullptr, out, nullptr, N, D_H);
}